// Round 5
// baseline (745.016 us; speedup 1.0000x reference)
//
#include <hip/hip_runtime.h>
#include <hip/hip_bf16.h>

#define BB 16
#define N1S 4096
#define N2S 1024
#define C1S 128
#define C2S 256
#define KIN0 384
#define KOUT0 256
#define KOUT1 128
#define EPS_DIST 1e-10f
#define BN_EPS 1e-5f

typedef __hip_bfloat16 bf16;

__device__ __forceinline__ float b2f(bf16 v) { return __bfloat162float(v); }

// ---------------- kernel 1: 3-NN + weights (fp32 inputs) ----------------
// grid (16 ntile, 16 b), block 256
__global__ __launch_bounds__(256) void knn_kernel(
    const float* __restrict__ xyz1, const float* __restrict__ xyz2,
    int* __restrict__ idxo, float* __restrict__ wo) {
  __shared__ float sx[N2S], sy[N2S], sz[N2S], sn[N2S];
  const int b = blockIdx.y;
  const int tid = threadIdx.x;
  const float* x2 = xyz2 + b * N2S * 3;
  for (int j = tid; j < N2S; j += 256) {
    float x = x2[j * 3 + 0];
    float y = x2[j * 3 + 1];
    float z = x2[j * 3 + 2];
    sx[j] = x; sy[j] = y; sz[j] = z;
    sn[j] = (x * x + y * y) + z * z;
  }
  __syncthreads();
  const int n = blockIdx.x * 256 + tid;
  const float* p1 = xyz1 + (b * N1S + n) * 3;
  const float ax = p1[0], ay = p1[1], az = p1[2];
  const float s1 = (ax * ax + ay * ay) + az * az;
  float d0 = 3.4e38f, d1 = 3.4e38f, d2 = 3.4e38f;
  int i0 = 0, i1 = 0, i2 = 0;
  for (int j = 0; j < N2S; ++j) {
    float dot = (ax * sx[j] + ay * sy[j]) + az * sz[j];
    float d = (s1 + sn[j]) - 2.0f * dot;
    d = fmaxf(d, EPS_DIST);
    if (d < d2) {
      if (d < d1) {
        d2 = d1; i2 = i1;
        if (d < d0) { d1 = d0; i1 = i0; d0 = d; i0 = j; }
        else { d1 = d; i1 = j; }
      } else { d2 = d; i2 = j; }
    }
  }
  float w0 = 1.0f / d0, w1 = 1.0f / d1, w2 = 1.0f / d2;
  float s = (w0 + w1) + w2;
  w0 /= s; w1 /= s; w2 /= s;
  const int base = (b * N1S + n) * 3;
  idxo[base + 0] = i0; idxo[base + 1] = i1; idxo[base + 2] = i2;
  wo[base + 0] = w0; wo[base + 1] = w1; wo[base + 2] = w2;
}

// ------ kernel 2: Z = W0[:,128:] * points2  (fp32, lives in d_out front) ------
// grid (16 mtile, 4 otile, 16 b), block 256 (16x16), 4x4 per thread
__global__ __launch_bounds__(256) void zgemm_kernel(
    const float* __restrict__ W0, const float* __restrict__ points2,
    float* __restrict__ Z) {
  __shared__ float As[16][68];  // [k][o]
  __shared__ float Bs[16][68];  // [k][m]
  const int b = blockIdx.z;
  const int o0 = blockIdx.y * 64;
  const int m0 = blockIdx.x * 64;
  const int tid = threadIdx.x;
  const int tx = tid & 15, ty = tid >> 4;
  float acc[4][4] = {};
  for (int k0 = 0; k0 < C2S; k0 += 16) {
    for (int t = tid; t < 1024; t += 256) {
      int r = t >> 4;
      int kk = t & 15;
      As[kk][r] = W0[(o0 + r) * KIN0 + C1S + k0 + kk];
    }
    for (int t = tid; t < 1024; t += 256) {
      int kk = t >> 6;
      int mm = t & 63;
      Bs[kk][mm] = points2[((b * C2S) + (k0 + kk)) * N2S + m0 + mm];
    }
    __syncthreads();
#pragma unroll
    for (int k = 0; k < 16; ++k) {
      float4 a = *(const float4*)&As[k][ty * 4];
      float4 x = *(const float4*)&Bs[k][tx * 4];
      float av[4] = {a.x, a.y, a.z, a.w};
      float xv[4] = {x.x, x.y, x.z, x.w};
#pragma unroll
      for (int i = 0; i < 4; ++i)
#pragma unroll
        for (int j = 0; j < 4; ++j) acc[i][j] += av[i] * xv[j];
    }
    __syncthreads();
  }
#pragma unroll
  for (int i = 0; i < 4; ++i) {
    const int o = o0 + ty * 4 + i;
#pragma unroll
    for (int j = 0; j < 4; ++j) {
      const int m = m0 + tx * 4 + j;
      Z[((b * C2S) + o) * N2S + m] = acc[i][j];
    }
  }
}

// ----- kernel 3: y0 = W0[:,:128]*points1 + gather(Z,w) + b0  (bf16 out) -----
// grid (64 ntile, 4 otile, 16 b), block 256 (16x16), 4x4 per thread
__global__ __launch_bounds__(256) void gemm0g_kernel(
    const float* __restrict__ W0, const float* __restrict__ b0,
    const float* __restrict__ points1, const float* __restrict__ Z,
    const int* __restrict__ idx, const float* __restrict__ wgt,
    bf16* __restrict__ y0) {
  __shared__ float As[16][68];
  __shared__ float Bs[16][68];
  __shared__ int sidx[192];    // 64 n x 3
  __shared__ float swgt[192];
  const int b = blockIdx.z;
  const int o0 = blockIdx.y * 64;
  const int n0 = blockIdx.x * 64;
  const int tid = threadIdx.x;
  const int tx = tid & 15, ty = tid >> 4;
  if (tid < 192) {
    sidx[tid] = idx[(b * N1S + n0) * 3 + tid];
    swgt[tid] = wgt[(b * N1S + n0) * 3 + tid];
  }
  float acc[4][4] = {};
  for (int k0 = 0; k0 < C1S; k0 += 16) {
    for (int t = tid; t < 1024; t += 256) {
      int r = t >> 4;
      int kk = t & 15;
      As[kk][r] = W0[(o0 + r) * KIN0 + k0 + kk];
    }
    for (int t = tid; t < 1024; t += 256) {
      int kk = t >> 6;
      int nn = t & 63;
      Bs[kk][nn] = points1[((b * C1S) + (k0 + kk)) * N1S + n0 + nn];
    }
    __syncthreads();
#pragma unroll
    for (int k = 0; k < 16; ++k) {
      float4 a = *(const float4*)&As[k][ty * 4];
      float4 x = *(const float4*)&Bs[k][tx * 4];
      float av[4] = {a.x, a.y, a.z, a.w};
      float xv[4] = {x.x, x.y, x.z, x.w};
#pragma unroll
      for (int i = 0; i < 4; ++i)
#pragma unroll
        for (int j = 0; j < 4; ++j) acc[i][j] += av[i] * xv[j];
    }
    __syncthreads();
  }
#pragma unroll
  for (int j = 0; j < 4; ++j) {
    const int nl = tx * 4 + j;
    const int n = n0 + nl;
    const int i0 = sidx[nl * 3 + 0], i1 = sidx[nl * 3 + 1], i2 = sidx[nl * 3 + 2];
    const float w0 = swgt[nl * 3 + 0], w1 = swgt[nl * 3 + 1], w2 = swgt[nl * 3 + 2];
#pragma unroll
    for (int i = 0; i < 4; ++i) {
      const int o = o0 + ty * 4 + i;
      const float* zrow = Z + ((b * C2S) + o) * N2S;
      float v = acc[i][j] + (w0 * zrow[i0] + w1 * zrow[i1]) + w2 * zrow[i2] + b0[o];
      y0[((b * KOUT0) + o) * N1S + n] = __float2bfloat16(v);
    }
  }
}

// ------------- kernel 4: per-channel mean + scale (bf16 input, C=256) ----------
__global__ __launch_bounds__(256) void stats_bf16_kernel(
    const bf16* __restrict__ y, const float* __restrict__ g,
    float* __restrict__ st, int C) {
  const int o = blockIdx.x;
  const int tid = threadIdx.x;
  float s = 0.f, ss = 0.f;
  for (int f = tid; f < BB * N1S; f += 256) {
    int b = f >> 12;
    int n = f & 4095;
    float v = b2f(y[((b * C) + o) * N1S + n]);
    s += v; ss += v * v;
  }
  __shared__ float rs[256], rss[256];
  rs[tid] = s; rss[tid] = ss;
  __syncthreads();
  for (int k = 128; k > 0; k >>= 1) {
    if (tid < k) { rs[tid] += rs[tid + k]; rss[tid] += rss[tid + k]; }
    __syncthreads();
  }
  if (tid == 0) {
    const float inv = 1.0f / (BB * N1S);
    float mean = rs[0] * inv;
    float var = rss[0] * inv - mean * mean;
    st[o] = mean;
    st[C + o] = g[o] / sqrtf(var + BN_EPS);
  }
}

// ------------- kernel 7: per-channel mean + scale (fp32 input, C=128) ----------
__global__ __launch_bounds__(256) void stats_f32_kernel(
    const float* __restrict__ y, const float* __restrict__ g,
    float* __restrict__ st, int C) {
  const int o = blockIdx.x;
  const int tid = threadIdx.x;
  float s = 0.f, ss = 0.f;
  for (int f = tid; f < BB * N1S; f += 256) {
    int b = f >> 12;
    int n = f & 4095;
    float v = y[((b * C) + o) * N1S + n];
    s += v; ss += v * v;
  }
  __shared__ float rs[256], rss[256];
  rs[tid] = s; rss[tid] = ss;
  __syncthreads();
  for (int k = 128; k > 0; k >>= 1) {
    if (tid < k) { rs[tid] += rs[tid + k]; rss[tid] += rss[tid + k]; }
    __syncthreads();
  }
  if (tid == 0) {
    const float inv = 1.0f / (BB * N1S);
    float mean = rs[0] * inv;
    float var = rss[0] * inv - mean * mean;
    st[o] = mean;
    st[C + o] = g[o] / sqrtf(var + BN_EPS);
  }
}

// ---------- kernel 5: BN + ReLU, bf16 in → bf16 out (in place ok) ----------
__global__ __launch_bounds__(256) void bnrelu_b_kernel(
    const bf16* y, const float* __restrict__ st,
    const float* __restrict__ be, bf16* out, int Cmask, int C) {
  const int i = blockIdx.x * 256 + threadIdx.x;
  const int bc = i >> 12;
  const int o = bc & Cmask;
  const float v = b2f(y[i]);
  const float r = (v - st[o]) * st[C + o] + be[o];
  out[i] = __float2bfloat16(fmaxf(r, 0.f));
}

// ---------- kernel 8: BN + ReLU, fp32 in → fp32 out (in place, d_out) ----------
__global__ __launch_bounds__(256) void bnrelu_f_kernel(
    const float* y, const float* __restrict__ st,
    const float* __restrict__ be, float* out, int Cmask, int C) {
  const int i = blockIdx.x * 256 + threadIdx.x;
  const int bc = i >> 12;
  const int o = bc & Cmask;
  const float v = y[i];
  const float r = (v - st[o]) * st[C + o] + be[o];
  out[i] = fmaxf(r, 0.f);
}

// ------- kernel 6: y1 = W1 * x1 + b1  (x1 bf16, fp32 out into d_out) -------
// grid (64 ntile, 2 otile, 16 b), block 256
__global__ __launch_bounds__(256) void gemm1_kernel(
    const float* __restrict__ W1, const float* __restrict__ b1,
    const bf16* __restrict__ x1, float* __restrict__ y1) {
  __shared__ float As[16][68];
  __shared__ float Bs[16][68];
  const int b = blockIdx.z;
  const int o0 = blockIdx.y * 64;
  const int n0 = blockIdx.x * 64;
  const int tid = threadIdx.x;
  const int tx = tid & 15, ty = tid >> 4;
  float acc[4][4] = {};
  for (int k0 = 0; k0 < C2S; k0 += 16) {
    for (int t = tid; t < 1024; t += 256) {
      int r = t >> 4;
      int kk = t & 15;
      As[kk][r] = W1[(o0 + r) * C2S + k0 + kk];
    }
    for (int t = tid; t < 1024; t += 256) {
      int kk = t >> 6;
      int nn = t & 63;
      Bs[kk][nn] = b2f(x1[((b * C2S) + (k0 + kk)) * N1S + n0 + nn]);
    }
    __syncthreads();
#pragma unroll
    for (int k = 0; k < 16; ++k) {
      float4 a = *(const float4*)&As[k][ty * 4];
      float4 x = *(const float4*)&Bs[k][tx * 4];
      float av[4] = {a.x, a.y, a.z, a.w};
      float xv[4] = {x.x, x.y, x.z, x.w};
#pragma unroll
      for (int i = 0; i < 4; ++i)
#pragma unroll
        for (int j = 0; j < 4; ++j) acc[i][j] += av[i] * xv[j];
    }
    __syncthreads();
  }
#pragma unroll
  for (int i = 0; i < 4; ++i) {
    const int o = o0 + ty * 4 + i;
    const float bias = b1[o];
#pragma unroll
    for (int j = 0; j < 4; ++j) {
      const int n = n0 + tx * 4 + j;
      y1[((b * KOUT1) + o) * N1S + n] = acc[i][j] + bias;
    }
  }
}

extern "C" void kernel_launch(void* const* d_in, const int* in_sizes, int n_in,
                              void* d_out, int out_size, void* d_ws, size_t ws_size,
                              hipStream_t stream) {
  (void)in_sizes; (void)n_in; (void)out_size; (void)ws_size;
  const float* xyz1    = (const float*)d_in[0];
  const float* xyz2    = (const float*)d_in[1];
  const float* points1 = (const float*)d_in[2];
  const float* points2 = (const float*)d_in[3];
  const float* W0  = (const float*)d_in[4];
  const float* b0  = (const float*)d_in[5];
  const float* g0  = (const float*)d_in[6];
  const float* be0 = (const float*)d_in[7];
  const float* W1  = (const float*)d_in[8];
  const float* b1  = (const float*)d_in[9];
  const float* g1  = (const float*)d_in[10];
  const float* be1 = (const float*)d_in[11];

  char* ws = (char*)d_ws;
  // workspace layout (bytes), total ~35.7 MB:
  //   [0,        768K)   idx  int   (B,N1,3)
  //   [768K,     1.5M)   wgt  fp32  (B,N1,3)
  //   [1572864,  +2K)    st0  fp32  512
  //   [1574912,  +1K)    st1  fp32  256
  //   [2M,       34M)    y0   bf16  (B,256,N1)   -- BN-ReLU'd in place
  // Z fp32 (B,256,1024) = 16.7 MB lives in the front of d_out (fp32, 33.5 MB);
  // Z is dead before gemm1 overwrites d_out with y1 (BN-ReLU'd in place).
  int*   idx = (int*)(ws + 0);
  float* wgt = (float*)(ws + 786432);
  float* st0 = (float*)(ws + 1572864);
  float* st1 = (float*)(ws + 1574912);
  bf16*  y0  = (bf16*)(ws + 2097152);
  float* Z   = (float*)d_out;
  float* y1  = (float*)d_out;

  knn_kernel<<<dim3(16, 16), 256, 0, stream>>>(xyz1, xyz2, idx, wgt);
  zgemm_kernel<<<dim3(16, 4, 16), 256, 0, stream>>>(W0, points2, Z);
  gemm0g_kernel<<<dim3(64, 4, 16), 256, 0, stream>>>(W0, b0, points1, Z, idx, wgt, y0);
  stats_bf16_kernel<<<256, 256, 0, stream>>>(y0, g0, st0, 256);
  bnrelu_b_kernel<<<65536, 256, 0, stream>>>(y0, st0, be0, y0, 255, 256);
  gemm1_kernel<<<dim3(64, 2, 16), 256, 0, stream>>>(W1, b1, y0, y1);
  stats_f32_kernel<<<128, 256, 0, stream>>>(y1, g1, st1, 128);
  bnrelu_f_kernel<<<32768, 256, 0, stream>>>(y1, st1, be1, y1, 127, 128);
}

// Round 6
// 405.741 us; speedup vs baseline: 1.8362x; 1.8362x over previous
//
#include <hip/hip_runtime.h>

#define EPS_DIST 1e-10f
#define BN_EPS 1e-5f

typedef short short8 __attribute__((ext_vector_type(8)));
typedef float floatx4 __attribute__((ext_vector_type(4)));

__device__ __forceinline__ unsigned short f2bf(float f) {
  unsigned u = __float_as_uint(f);
  unsigned r = (u + 0x7FFFu + ((u >> 16) & 1u)) >> 16;  // RNE
  return (unsigned short)r;
}
__device__ __forceinline__ float bf2f(unsigned short h) {
  return __uint_as_float(((unsigned)h) << 16);
}

// ---------------- kernel 1: 3-NN + weights (fp32) ----------------
// grid (16 ntile, 16 b), block 256
__global__ __launch_bounds__(256) void knn_kernel(
    const float* __restrict__ xyz1, const float* __restrict__ xyz2,
    int* __restrict__ idxo, float* __restrict__ wo) {
  __shared__ float sx[1024], sy[1024], sz[1024], sn[1024];
  const int b = blockIdx.y;
  const int tid = threadIdx.x;
  const float* x2 = xyz2 + b * 1024 * 3;
  for (int j = tid; j < 1024; j += 256) {
    float x = x2[j * 3 + 0], y = x2[j * 3 + 1], z = x2[j * 3 + 2];
    sx[j] = x; sy[j] = y; sz[j] = z;
    sn[j] = (x * x + y * y) + z * z;
  }
  __syncthreads();
  const int n = blockIdx.x * 256 + tid;
  const float* p1 = xyz1 + (b * 4096 + n) * 3;
  const float ax = p1[0], ay = p1[1], az = p1[2];
  const float s1 = (ax * ax + ay * ay) + az * az;
  float d0 = 3.4e38f, d1 = 3.4e38f, d2 = 3.4e38f;
  int i0 = 0, i1 = 0, i2 = 0;
  for (int j = 0; j < 1024; ++j) {
    float dot = (ax * sx[j] + ay * sy[j]) + az * sz[j];
    float d = (s1 + sn[j]) - 2.0f * dot;
    d = fmaxf(d, EPS_DIST);
    if (d < d2) {
      if (d < d1) {
        d2 = d1; i2 = i1;
        if (d < d0) { d1 = d0; i1 = i0; d0 = d; i0 = j; }
        else { d1 = d; i1 = j; }
      } else { d2 = d; i2 = j; }
    }
  }
  float w0 = 1.0f / d0, w1 = 1.0f / d1, w2 = 1.0f / d2;
  float s = (w0 + w1) + w2;
  w0 /= s; w1 /= s; w2 /= s;
  const int base = (b * 4096 + n) * 3;
  idxo[base + 0] = i0; idxo[base + 1] = i1; idxo[base + 2] = i2;
  wo[base + 0] = w0; wo[base + 1] = w1; wo[base + 2] = w2;
}

// ---------------- cvt_w: W0 (256x384) ++ W1 (128x256) -> bf16 ----------------
__global__ __launch_bounds__(256) void cvt_w_kernel(
    const float* __restrict__ W0, const float* __restrict__ W1,
    unsigned short* __restrict__ Wb) {
  int i = blockIdx.x * 256 + threadIdx.x;  // 131072 total
  float v = (i < 98304) ? W0[i] : W1[i - 98304];
  Wb[i] = f2bf(v);
}

// ------- tcvt: src fp32 [B][K][N] -> dst bf16 [B][N][K]; grid (N/64, K/64, B) -------
__global__ __launch_bounds__(256) void tcvt_kernel(
    const float* __restrict__ src, unsigned short* __restrict__ dst,
    int K, int N) {
  __shared__ float sm[64][65];
  const int n0 = blockIdx.x * 64, k0 = blockIdx.y * 64, b = blockIdx.z;
  const int tid = threadIdx.x;
  const int nl = tid & 63, kq = tid >> 6;
  const float* s = src + ((size_t)b * K + k0) * N + n0;
#pragma unroll
  for (int p = 0; p < 16; ++p) {
    int kl = p * 4 + kq;
    sm[kl][nl] = s[(size_t)kl * N + nl];
  }
  __syncthreads();
#pragma unroll
  for (int p = 0; p < 2; ++p) {
    int c = p * 256 + tid;
    int rn = c >> 3, jj = c & 7;
    short8 v;
#pragma unroll
    for (int u = 0; u < 8; ++u) v[u] = (short)f2bf(sm[jj * 8 + u][rn]);
    *(short8*)(dst + (size_t)(b * N + n0 + rn) * K + k0 + jj * 8) = v;
  }
}

// ---- zgemm: Zt[b][1024][256] fp32 = W0b[:,128:384] * Xt2 ; grid (8, 4, 16) ----
__global__ __launch_bounds__(256) void zgemm_kernel(
    const unsigned short* __restrict__ Wb, const unsigned short* __restrict__ Xt2,
    float* __restrict__ Zt) {
  __shared__ short sA[64 * 32];    // 64 o-rows x 32 k
  __shared__ short sB[128 * 32];   // 128 m-rows x 32 k
  const int b = blockIdx.z, o0 = blockIdx.y * 64, m0 = blockIdx.x * 128;
  const int tid = threadIdx.x, lane = tid & 63, w = tid >> 6;
  const int wo = w >> 1, wn = w & 1, quad = lane >> 4, l15 = lane & 15;
  floatx4 acc[2][4] = {};
  for (int kb = 0; kb < 256; kb += 32) {
    __syncthreads();
    {
      int r = tid >> 2, jj = tid & 3;
      *(short8*)(sA + tid * 8) =
          *(const short8*)(Wb + (size_t)(o0 + r) * 384 + 128 + kb + jj * 8);
    }
#pragma unroll
    for (int p = 0; p < 2; ++p) {
      int c = p * 256 + tid;
      int r = c >> 2, jj = c & 3;
      *(short8*)(sB + c * 8) =
          *(const short8*)(Xt2 + (size_t)(b * 1024 + m0 + r) * 256 + kb + jj * 8);
    }
    __syncthreads();
    short8 av[2], bv[4];
#pragma unroll
    for (int i = 0; i < 2; ++i)
      av[i] = *(const short8*)(sA + (wo * 32 + i * 16 + l15) * 32 + quad * 8);
#pragma unroll
    for (int j = 0; j < 4; ++j)
      bv[j] = *(const short8*)(sB + (wn * 64 + j * 16 + l15) * 32 + quad * 8);
#pragma unroll
    for (int i = 0; i < 2; ++i)
#pragma unroll
      for (int j = 0; j < 4; ++j)
        acc[i][j] = __builtin_amdgcn_mfma_f32_16x16x32_bf16(av[i], bv[j], acc[i][j], 0, 0, 0);
  }
#pragma unroll
  for (int i = 0; i < 2; ++i) {
    int ob = o0 + wo * 32 + i * 16 + quad * 4;
#pragma unroll
    for (int j = 0; j < 4; ++j) {
      int m = m0 + wn * 64 + j * 16 + l15;
      *(floatx4*)(Zt + (size_t)(b * 1024 + m) * 256 + ob) = acc[i][j];
    }
  }
}

// -- gemm0: y0t[b][4096][256] bf16 = W0b[:,:128]*Xt1 + gather(Zt,w) + b0 ; grid (32,4,16) --
__global__ __launch_bounds__(256) void gemm0_kernel(
    const unsigned short* __restrict__ Wb, const unsigned short* __restrict__ Xt1,
    const float* __restrict__ Zt, const int* __restrict__ idx,
    const float* __restrict__ wgt, const float* __restrict__ b0,
    unsigned short* __restrict__ y0t) {
  __shared__ short sA[64 * 32];    // 64 o-rows x 32 k
  __shared__ short sB[128 * 32];   // 128 n-rows x 32 k
  __shared__ int sidx[384];
  __shared__ float swgt[384];
  const int b = blockIdx.z, o0 = blockIdx.y * 64, n0 = blockIdx.x * 128;
  const int tid = threadIdx.x, lane = tid & 63, w = tid >> 6;
  const int wo = w >> 1, wn = w & 1, quad = lane >> 4, l15 = lane & 15;
  for (int t = tid; t < 384; t += 256) {
    sidx[t] = idx[(size_t)(b * 4096 + n0) * 3 + t];
    swgt[t] = wgt[(size_t)(b * 4096 + n0) * 3 + t];
  }
  floatx4 acc[2][4] = {};
  for (int kb = 0; kb < 128; kb += 32) {
    __syncthreads();
    {
      int r = tid >> 2, jj = tid & 3;
      *(short8*)(sA + tid * 8) =
          *(const short8*)(Wb + (size_t)(o0 + r) * 384 + kb + jj * 8);
    }
#pragma unroll
    for (int p = 0; p < 2; ++p) {
      int c = p * 256 + tid;
      int r = c >> 2, jj = c & 3;
      *(short8*)(sB + c * 8) =
          *(const short8*)(Xt1 + (size_t)(b * 4096 + n0 + r) * 128 + kb + jj * 8);
    }
    __syncthreads();
    short8 av[2], bv[4];
#pragma unroll
    for (int i = 0; i < 2; ++i)
      av[i] = *(const short8*)(sA + (wo * 32 + i * 16 + l15) * 32 + quad * 8);
#pragma unroll
    for (int j = 0; j < 4; ++j)
      bv[j] = *(const short8*)(sB + (wn * 64 + j * 16 + l15) * 32 + quad * 8);
#pragma unroll
    for (int i = 0; i < 2; ++i)
#pragma unroll
      for (int j = 0; j < 4; ++j)
        acc[i][j] = __builtin_amdgcn_mfma_f32_16x16x32_bf16(av[i], bv[j], acc[i][j], 0, 0, 0);
  }
  const float* zb = Zt + (size_t)b * 1024 * 256;
#pragma unroll
  for (int i = 0; i < 2; ++i) {
    int ob = o0 + wo * 32 + i * 16 + quad * 4;
    floatx4 bias = *(const floatx4*)(b0 + ob);
#pragma unroll
    for (int j = 0; j < 4; ++j) {
      int nl = wn * 64 + j * 16 + l15;
      int n = n0 + nl;
      int g0i = sidx[nl * 3 + 0], g1i = sidx[nl * 3 + 1], g2i = sidx[nl * 3 + 2];
      float gw0 = swgt[nl * 3 + 0], gw1 = swgt[nl * 3 + 1], gw2 = swgt[nl * 3 + 2];
      floatx4 z0 = *(const floatx4*)(zb + (size_t)g0i * 256 + ob);
      floatx4 z1 = *(const floatx4*)(zb + (size_t)g1i * 256 + ob);
      floatx4 z2 = *(const floatx4*)(zb + (size_t)g2i * 256 + ob);
      ushort4 out;
      float v0 = acc[i][j][0] + gw0 * z0[0] + gw1 * z1[0] + gw2 * z2[0] + bias[0];
      float v1 = acc[i][j][1] + gw0 * z0[1] + gw1 * z1[1] + gw2 * z2[1] + bias[1];
      float v2 = acc[i][j][2] + gw0 * z0[2] + gw1 * z1[2] + gw2 * z2[2] + bias[2];
      float v3 = acc[i][j][3] + gw0 * z0[3] + gw1 * z1[3] + gw2 * z2[3] + bias[3];
      out.x = f2bf(v0); out.y = f2bf(v1); out.z = f2bf(v2); out.w = f2bf(v3);
      *(ushort4*)(y0t + (size_t)(b * 4096 + n) * 256 + ob) = out;
    }
  }
}

// ---------------- stats0: per-o sums over y0t rows (atomic) ----------------
// grid 256 blocks x 256 thr; thread t <-> channel o=t
__global__ __launch_bounds__(256) void stats0_kernel(
    const unsigned short* __restrict__ y0t, float* __restrict__ acc0) {
  const int o = threadIdx.x;
  const size_t row0 = (size_t)blockIdx.x * 256;
  float s = 0.f, ss = 0.f;
  for (int r = 0; r < 256; ++r) {
    float v = bf2f(y0t[(row0 + r) * 256 + o]);
    s += v; ss += v * v;
  }
  atomicAdd(&acc0[o], s);
  atomicAdd(&acc0[256 + o], ss);
}

__global__ __launch_bounds__(256) void finalize0_kernel(
    const float* __restrict__ acc0, const float* __restrict__ g0,
    float* __restrict__ st0) {
  int o = threadIdx.x;
  const float inv = 1.0f / 65536.0f;
  float mean = acc0[o] * inv;
  float var = acc0[256 + o] * inv - mean * mean;
  st0[o] = mean;
  st0[256 + o] = g0[o] / sqrtf(var + BN_EPS);
}

// ------- bnrelu_t: in-place BN+ReLU on y0t (o contiguous), ushort4/thread -------
// grid 16384 x 256
__global__ __launch_bounds__(256) void bnrelu_t_kernel(
    unsigned short* __restrict__ y0t, const float* __restrict__ st0,
    const float* __restrict__ be0) {
  size_t i = (size_t)blockIdx.x * 256 + threadIdx.x;  // ushort4 index
  int o = (int)((i * 4) & 255);
  ushort4 v = ((ushort4*)y0t)[i];
  floatx4 m = *(const floatx4*)(st0 + o);
  floatx4 sc = *(const floatx4*)(st0 + 256 + o);
  floatx4 be = *(const floatx4*)(be0 + o);
  ushort4 r;
  r.x = f2bf(fmaxf((bf2f(v.x) - m[0]) * sc[0] + be[0], 0.f));
  r.y = f2bf(fmaxf((bf2f(v.y) - m[1]) * sc[1] + be[1], 0.f));
  r.z = f2bf(fmaxf((bf2f(v.z) - m[2]) * sc[2] + be[2], 0.f));
  r.w = f2bf(fmaxf((bf2f(v.w) - m[3]) * sc[3] + be[3], 0.f));
  ((ushort4*)y0t)[i] = r;
}

// ---- gemm1: y1[b][128][4096] fp32 (d_out) = W1b * x1t^T + b1 ; grid (32, 2, 16) ----
__global__ __launch_bounds__(256) void gemm1_kernel(
    const unsigned short* __restrict__ Wb, const unsigned short* __restrict__ x1t,
    const float* __restrict__ b1, float* __restrict__ y1) {
  __shared__ short sA[128 * 32];   // 128 n-rows x 32 k
  __shared__ short sB[64 * 32];    // 64 o-rows x 32 k
  const int b = blockIdx.z, o0 = blockIdx.y * 64, n0 = blockIdx.x * 128;
  const int tid = threadIdx.x, lane = tid & 63, w = tid >> 6;
  const int wm = w & 1, wo2 = w >> 1, quad = lane >> 4, l15 = lane & 15;
  const unsigned short* W1b = Wb + 98304;
  floatx4 acc[4][2] = {};
  for (int kb = 0; kb < 256; kb += 32) {
    __syncthreads();
#pragma unroll
    for (int p = 0; p < 2; ++p) {
      int c = p * 256 + tid;
      int r = c >> 2, jj = c & 3;
      *(short8*)(sA + c * 8) =
          *(const short8*)(x1t + (size_t)(b * 4096 + n0 + r) * 256 + kb + jj * 8);
    }
    {
      int r = tid >> 2, jj = tid & 3;
      *(short8*)(sB + tid * 8) =
          *(const short8*)(W1b + (size_t)(o0 + r) * 256 + kb + jj * 8);
    }
    __syncthreads();
    short8 av[4], bv[2];
#pragma unroll
    for (int i = 0; i < 4; ++i)
      av[i] = *(const short8*)(sA + (wm * 64 + i * 16 + l15) * 32 + quad * 8);
#pragma unroll
    for (int j = 0; j < 2; ++j)
      bv[j] = *(const short8*)(sB + (wo2 * 32 + j * 16 + l15) * 32 + quad * 8);
#pragma unroll
    for (int i = 0; i < 4; ++i)
#pragma unroll
      for (int j = 0; j < 2; ++j)
        acc[i][j] = __builtin_amdgcn_mfma_f32_16x16x32_bf16(av[i], bv[j], acc[i][j], 0, 0, 0);
  }
#pragma unroll
  for (int i = 0; i < 4; ++i) {
    int n = n0 + wm * 64 + i * 16 + quad * 4;
#pragma unroll
    for (int j = 0; j < 2; ++j) {
      int o = o0 + wo2 * 32 + j * 16 + l15;
      floatx4 v = acc[i][j] + b1[o];
      *(floatx4*)(y1 + (size_t)(b * 128 + o) * 4096 + n) = v;
    }
  }
}

// ---------------- stats1: per-channel mean + scale (fp32, C=128) ----------------
__global__ __launch_bounds__(256) void stats1_kernel(
    const float* __restrict__ y, const float* __restrict__ g,
    float* __restrict__ st) {
  const int o = blockIdx.x;
  const int tid = threadIdx.x;
  float s = 0.f, ss = 0.f;
  for (int f = tid; f < 16 * 4096; f += 256) {
    int b = f >> 12;
    int n = f & 4095;
    float v = y[(size_t)((b * 128) + o) * 4096 + n];
    s += v; ss += v * v;
  }
  __shared__ float rs[256], rss[256];
  rs[tid] = s; rss[tid] = ss;
  __syncthreads();
  for (int k = 128; k > 0; k >>= 1) {
    if (tid < k) { rs[tid] += rs[tid + k]; rss[tid] += rss[tid + k]; }
    __syncthreads();
  }
  if (tid == 0) {
    const float inv = 1.0f / 65536.0f;
    float mean = rs[0] * inv;
    float var = rss[0] * inv - mean * mean;
    st[o] = mean;
    st[128 + o] = g[o] / sqrtf(var + BN_EPS);
  }
}

// ---------------- bnrelu_f: fp32 in place on d_out ----------------
__global__ __launch_bounds__(256) void bnrelu_f_kernel(
    float* __restrict__ y, const float* __restrict__ st,
    const float* __restrict__ be) {
  size_t i = (size_t)blockIdx.x * 256 + threadIdx.x;
  int o = (int)(i >> 12) & 127;
  float v = y[i];
  float r = (v - st[o]) * st[128 + o] + be[o];
  y[i] = fmaxf(r, 0.f);
}

extern "C" void kernel_launch(void* const* d_in, const int* in_sizes, int n_in,
                              void* d_out, int out_size, void* d_ws, size_t ws_size,
                              hipStream_t stream) {
  (void)in_sizes; (void)n_in; (void)out_size; (void)ws_size;
  const float* xyz1    = (const float*)d_in[0];
  const float* xyz2    = (const float*)d_in[1];
  const float* points1 = (const float*)d_in[2];
  const float* points2 = (const float*)d_in[3];
  const float* W0  = (const float*)d_in[4];
  const float* b0  = (const float*)d_in[5];
  const float* g0  = (const float*)d_in[6];
  const float* be0 = (const float*)d_in[7];
  const float* W1  = (const float*)d_in[8];
  const float* b1  = (const float*)d_in[9];
  const float* g1  = (const float*)d_in[10];
  const float* be1 = (const float*)d_in[11];

  char* ws = (char*)d_ws;
  // layout (bytes), ~58 MB total:
  //   [0,        768K)   idx  int  (B,N1,3)
  //   [768K,     1.5M)   wgt  f32  (B,N1,3)
  //   [1572864,  +2K)    st0  f32[512]
  //   [1574912,  +1K)    st1  f32[256]
  //   [1576960,  +2K)    acc0 f32[512] (zeroed via memset)
  //   [1581056,  +256K)  Wb   bf16 (W0b 98304 ++ W1b 32768)
  //   [2M,       10M)    Xt2  bf16 (B,1024,256)
  //   [10M,      26M)    Xt1  bf16 (B,4096,128)
  //   [26M,      58M)    y0t  bf16 (B,4096,256)  -- BN-ReLU'd in place
  // Zt fp32 (B,1024,256) = 16 MB lives in d_out front; dead before gemm1.
  int*   idx  = (int*)(ws + 0);
  float* wgt  = (float*)(ws + 786432);
  float* st0  = (float*)(ws + 1572864);
  float* st1  = (float*)(ws + 1574912);
  float* acc0 = (float*)(ws + 1576960);
  unsigned short* Wb  = (unsigned short*)(ws + 1581056);
  unsigned short* Xt2 = (unsigned short*)(ws + 2097152);
  unsigned short* Xt1 = (unsigned short*)(ws + 10485760);
  unsigned short* y0t = (unsigned short*)(ws + 27262976);
  float* Zt = (float*)d_out;
  float* y1 = (float*)d_out;

  cvt_w_kernel<<<512, 256, 0, stream>>>(W0, W1, Wb);
  knn_kernel<<<dim3(16, 16), 256, 0, stream>>>(xyz1, xyz2, idx, wgt);
  tcvt_kernel<<<dim3(16, 4, 16), 256, 0, stream>>>(points2, Xt2, 256, 1024);
  tcvt_kernel<<<dim3(64, 2, 16), 256, 0, stream>>>(points1, Xt1, 128, 4096);
  zgemm_kernel<<<dim3(8, 4, 16), 256, 0, stream>>>(Wb, Xt2, Zt);
  gemm0_kernel<<<dim3(32, 4, 16), 256, 0, stream>>>(Wb, Xt1, Zt, idx, wgt, b0, y0t);
  hipMemsetAsync(acc0, 0, 2048, stream);
  stats0_kernel<<<256, 256, 0, stream>>>(y0t, acc0);
  finalize0_kernel<<<1, 256, 0, stream>>>(acc0, g0, st0);
  bnrelu_t_kernel<<<16384, 256, 0, stream>>>(y0t, st0, be0);
  gemm1_kernel<<<dim3(32, 2, 16), 256, 0, stream>>>(Wb, y0t, b1, y1);
  stats1_kernel<<<128, 256, 0, stream>>>(y1, g1, st1);
  bnrelu_f_kernel<<<32768, 256, 0, stream>>>(y1, st1, be1);
}

// Round 7
// 337.561 us; speedup vs baseline: 2.2071x; 1.2020x over previous
//
#include <hip/hip_runtime.h>

#define EPS_DIST 1e-10f
#define BN_EPS 1e-5f

typedef short short8 __attribute__((ext_vector_type(8)));
typedef float floatx4 __attribute__((ext_vector_type(4)));

__device__ __forceinline__ unsigned short f2bf(float f) {
  unsigned u = __float_as_uint(f);
  unsigned r = (u + 0x7FFFu + ((u >> 16) & 1u)) >> 16;  // RNE
  return (unsigned short)r;
}
__device__ __forceinline__ float bf2f(unsigned short h) {
  return __uint_as_float(((unsigned)h) << 16);
}

// ---------------- kernel 1: 3-NN + weights, 8 lanes per query ----------------
// grid (128 qtile, 16 b), block 256 (32 queries x 8 lanes)
__global__ __launch_bounds__(256) void knn_kernel(
    const float* __restrict__ xyz1, const float* __restrict__ xyz2,
    int* __restrict__ idxo, float* __restrict__ wo) {
  __shared__ float4 s2[1024];  // x,y,z,|.|^2
  const int b = blockIdx.y;
  const int tid = threadIdx.x;
  const float* x2 = xyz2 + b * 3072;
  for (int j = tid; j < 1024; j += 256) {
    float x = x2[j * 3 + 0], y = x2[j * 3 + 1], z = x2[j * 3 + 2];
    s2[j] = make_float4(x, y, z, (x * x + y * y) + z * z);
  }
  __syncthreads();
  const int q = tid >> 3, sub = tid & 7;
  const int n = blockIdx.x * 32 + q;
  const float* p1 = xyz1 + (b * 4096 + n) * 3;
  const float ax = p1[0], ay = p1[1], az = p1[2];
  const float s1 = (ax * ax + ay * ay) + az * az;
  float d0 = 3.4e38f, d1 = 3.4e38f, d2 = 3.4e38f;
  int i0 = 0x7fffffff, i1 = 0x7fffffff, i2 = 0x7fffffff;
  // lane `sub` scans j = jj*8+sub: 8 distinct b128 addrs/wave hit disjoint
  // bank quads (conflict-free), 8 lanes broadcast per addr.
  for (int jj = 0; jj < 128; ++jj) {
    int j = jj * 8 + sub;
    float4 c = s2[j];
    float dot = (ax * c.x + ay * c.y) + az * c.z;
    float d = (s1 + c.w) - 2.0f * dot;
    d = fmaxf(d, EPS_DIST);
    if (d < d2) {
      if (d < d1) {
        d2 = d1; i2 = i1;
        if (d < d0) { d1 = d0; i1 = i0; d0 = d; i0 = j; }
        else { d1 = d; i1 = j; }
      } else { d2 = d; i2 = j; }
    }
  }
  // butterfly merge of sorted triples across the 8-lane group.
  // lexicographic (d, idx) compare == lax.top_k stable lowest-index tie-break.
#pragma unroll
  for (int m = 1; m <= 4; m <<= 1) {
    float e0 = __shfl_xor(d0, m), e1 = __shfl_xor(d1, m), e2 = __shfl_xor(d2, m);
    int   f0 = __shfl_xor(i0, m), f1 = __shfl_xor(i1, m), f2 = __shfl_xor(i2, m);
    float A[3] = {d0, d1, d2}, Bv[3] = {e0, e1, e2};
    int   I[3] = {i0, i1, i2}, J[3] = {f0, f1, f2};
    float md[3]; int mi[3];
    int pa = 0, pb = 0;
#pragma unroll
    for (int k = 0; k < 3; ++k) {
      float da = A[pa], db = Bv[pb];
      int ia = I[pa], ib = J[pb];
      bool ta = (da < db) || (da == db && ia < ib);
      md[k] = ta ? da : db; mi[k] = ta ? ia : ib;
      pa += ta ? 1 : 0; pb += ta ? 0 : 1;
    }
    d0 = md[0]; d1 = md[1]; d2 = md[2];
    i0 = mi[0]; i1 = mi[1]; i2 = mi[2];
  }
  if (sub == 0) {
    float w0 = 1.0f / d0, w1 = 1.0f / d1, w2 = 1.0f / d2;
    float s = (w0 + w1) + w2;
    w0 /= s; w1 /= s; w2 /= s;
    const int base = (b * 4096 + n) * 3;
    idxo[base + 0] = i0; idxo[base + 1] = i1; idxo[base + 2] = i2;
    wo[base + 0] = w0; wo[base + 1] = w1; wo[base + 2] = w2;
  }
}

// ---------------- cvt_w: W0 (256x384) ++ W1 (128x256) -> bf16 ----------------
__global__ __launch_bounds__(256) void cvt_w_kernel(
    const float* __restrict__ W0, const float* __restrict__ W1,
    unsigned short* __restrict__ Wb) {
  int i = blockIdx.x * 256 + threadIdx.x;  // 131072 total
  float v = (i < 98304) ? W0[i] : W1[i - 98304];
  Wb[i] = f2bf(v);
}

// ------- tcvt: src fp32 [B][K][N] -> dst bf16 [B][N][K]; grid (N/64, K/64, B) -------
__global__ __launch_bounds__(256) void tcvt_kernel(
    const float* __restrict__ src, unsigned short* __restrict__ dst,
    int K, int N) {
  __shared__ float sm[64][65];
  const int n0 = blockIdx.x * 64, k0 = blockIdx.y * 64, b = blockIdx.z;
  const int tid = threadIdx.x;
  const int nl = tid & 63, kq = tid >> 6;
  const float* s = src + ((size_t)b * K + k0) * N + n0;
#pragma unroll
  for (int p = 0; p < 16; ++p) {
    int kl = p * 4 + kq;
    sm[kl][nl] = s[(size_t)kl * N + nl];
  }
  __syncthreads();
#pragma unroll
  for (int p = 0; p < 2; ++p) {
    int c = p * 256 + tid;
    int rn = c >> 3, jj = c & 7;
    short8 v;
#pragma unroll
    for (int u = 0; u < 8; ++u) v[u] = (short)f2bf(sm[jj * 8 + u][rn]);
    *(short8*)(dst + (size_t)(b * N + n0 + rn) * K + k0 + jj * 8) = v;
  }
}

// ---- zgemm: Zt[b][1024][256] fp32 = W0b[:,128:384] * Xt2 ; grid (8, 4, 16) ----
__global__ __launch_bounds__(256) void zgemm_kernel(
    const unsigned short* __restrict__ Wb, const unsigned short* __restrict__ Xt2,
    float* __restrict__ Zt) {
  __shared__ short sA[64 * 32];    // 64 o-rows x 32 k
  __shared__ short sB[128 * 32];   // 128 m-rows x 32 k
  const int b = blockIdx.z, o0 = blockIdx.y * 64, m0 = blockIdx.x * 128;
  const int tid = threadIdx.x, lane = tid & 63, w = tid >> 6;
  const int wo = w >> 1, wn = w & 1, quad = lane >> 4, l15 = lane & 15;
  floatx4 acc[2][4] = {};
  for (int kb = 0; kb < 256; kb += 32) {
    __syncthreads();
    {
      int r = tid >> 2, jj = tid & 3;
      *(short8*)(sA + tid * 8) =
          *(const short8*)(Wb + (size_t)(o0 + r) * 384 + 128 + kb + jj * 8);
    }
#pragma unroll
    for (int p = 0; p < 2; ++p) {
      int c = p * 256 + tid;
      int r = c >> 2, jj = c & 3;
      *(short8*)(sB + c * 8) =
          *(const short8*)(Xt2 + (size_t)(b * 1024 + m0 + r) * 256 + kb + jj * 8);
    }
    __syncthreads();
    short8 av[2], bv[4];
#pragma unroll
    for (int i = 0; i < 2; ++i)
      av[i] = *(const short8*)(sA + (wo * 32 + i * 16 + l15) * 32 + quad * 8);
#pragma unroll
    for (int j = 0; j < 4; ++j)
      bv[j] = *(const short8*)(sB + (wn * 64 + j * 16 + l15) * 32 + quad * 8);
#pragma unroll
    for (int i = 0; i < 2; ++i)
#pragma unroll
      for (int j = 0; j < 4; ++j)
        acc[i][j] = __builtin_amdgcn_mfma_f32_16x16x32_bf16(av[i], bv[j], acc[i][j], 0, 0, 0);
  }
#pragma unroll
  for (int i = 0; i < 2; ++i) {
    int ob = o0 + wo * 32 + i * 16 + quad * 4;
#pragma unroll
    for (int j = 0; j < 4; ++j) {
      int m = m0 + wn * 64 + j * 16 + l15;
      *(floatx4*)(Zt + (size_t)(b * 1024 + m) * 256 + ob) = acc[i][j];
    }
  }
}

// -- gemm0: y0t[b][4096][256] bf16 = W0b[:,:128]*Xt1 + gather(Zt,w) + b0 ; grid (32,4,16) --
__global__ __launch_bounds__(256) void gemm0_kernel(
    const unsigned short* __restrict__ Wb, const unsigned short* __restrict__ Xt1,
    const float* __restrict__ Zt, const int* __restrict__ idx,
    const float* __restrict__ wgt, const float* __restrict__ b0,
    unsigned short* __restrict__ y0t) {
  __shared__ short sA[64 * 32];    // 64 o-rows x 32 k
  __shared__ short sB[128 * 32];   // 128 n-rows x 32 k
  __shared__ int sidx[384];
  __shared__ float swgt[384];
  const int b = blockIdx.z, o0 = blockIdx.y * 64, n0 = blockIdx.x * 128;
  const int tid = threadIdx.x, lane = tid & 63, w = tid >> 6;
  const int wo = w >> 1, wn = w & 1, quad = lane >> 4, l15 = lane & 15;
  for (int t = tid; t < 384; t += 256) {
    sidx[t] = idx[(size_t)(b * 4096 + n0) * 3 + t];
    swgt[t] = wgt[(size_t)(b * 4096 + n0) * 3 + t];
  }
  floatx4 acc[2][4] = {};
  for (int kb = 0; kb < 128; kb += 32) {
    __syncthreads();
    {
      int r = tid >> 2, jj = tid & 3;
      *(short8*)(sA + tid * 8) =
          *(const short8*)(Wb + (size_t)(o0 + r) * 384 + kb + jj * 8);
    }
#pragma unroll
    for (int p = 0; p < 2; ++p) {
      int c = p * 256 + tid;
      int r = c >> 2, jj = c & 3;
      *(short8*)(sB + c * 8) =
          *(const short8*)(Xt1 + (size_t)(b * 4096 + n0 + r) * 128 + kb + jj * 8);
    }
    __syncthreads();
    short8 av[2], bv[4];
#pragma unroll
    for (int i = 0; i < 2; ++i)
      av[i] = *(const short8*)(sA + (wo * 32 + i * 16 + l15) * 32 + quad * 8);
#pragma unroll
    for (int j = 0; j < 4; ++j)
      bv[j] = *(const short8*)(sB + (wn * 64 + j * 16 + l15) * 32 + quad * 8);
#pragma unroll
    for (int i = 0; i < 2; ++i)
#pragma unroll
      for (int j = 0; j < 4; ++j)
        acc[i][j] = __builtin_amdgcn_mfma_f32_16x16x32_bf16(av[i], bv[j], acc[i][j], 0, 0, 0);
  }
  const float* zb = Zt + (size_t)b * 1024 * 256;
#pragma unroll
  for (int i = 0; i < 2; ++i) {
    int ob = o0 + wo * 32 + i * 16 + quad * 4;
    floatx4 bias = *(const floatx4*)(b0 + ob);
#pragma unroll
    for (int j = 0; j < 4; ++j) {
      int nl = wn * 64 + j * 16 + l15;
      int n = n0 + nl;
      int g0i = sidx[nl * 3 + 0], g1i = sidx[nl * 3 + 1], g2i = sidx[nl * 3 + 2];
      float gw0 = swgt[nl * 3 + 0], gw1 = swgt[nl * 3 + 1], gw2 = swgt[nl * 3 + 2];
      floatx4 z0 = *(const floatx4*)(zb + (size_t)g0i * 256 + ob);
      floatx4 z1 = *(const floatx4*)(zb + (size_t)g1i * 256 + ob);
      floatx4 z2 = *(const floatx4*)(zb + (size_t)g2i * 256 + ob);
      ushort4 out;
      float v0 = acc[i][j][0] + gw0 * z0[0] + gw1 * z1[0] + gw2 * z2[0] + bias[0];
      float v1 = acc[i][j][1] + gw0 * z0[1] + gw1 * z1[1] + gw2 * z2[1] + bias[1];
      float v2 = acc[i][j][2] + gw0 * z0[2] + gw1 * z1[2] + gw2 * z2[2] + bias[2];
      float v3 = acc[i][j][3] + gw0 * z0[3] + gw1 * z1[3] + gw2 * z2[3] + bias[3];
      out.x = f2bf(v0); out.y = f2bf(v1); out.z = f2bf(v2); out.w = f2bf(v3);
      *(ushort4*)(y0t + (size_t)(b * 4096 + n) * 256 + ob) = out;
    }
  }
}

// -------- stats0: per-channel sums over y0t (ushort4 loads + LDS reduce) --------
// grid 256 blocks x 256 thr
__global__ __launch_bounds__(256) void stats0_kernel(
    const unsigned short* __restrict__ y0t, float* __restrict__ acc0) {
  __shared__ float ls[512];
  const int tid = threadIdx.x;
  ls[tid] = 0.f; ls[256 + tid] = 0.f;
  __syncthreads();
  const int c4 = (tid & 63) * 4;
  const int rg = tid >> 6;
  const size_t row0 = (size_t)blockIdx.x * 256;
  float s0 = 0, s1 = 0, s2 = 0, s3 = 0, q0 = 0, q1 = 0, q2 = 0, q3 = 0;
  for (int r = rg; r < 256; r += 4) {
    ushort4 v = *(const ushort4*)(y0t + (row0 + r) * 256 + c4);
    float a = bf2f(v.x), bb = bf2f(v.y), c = bf2f(v.z), d = bf2f(v.w);
    s0 += a; s1 += bb; s2 += c; s3 += d;
    q0 += a * a; q1 += bb * bb; q2 += c * c; q3 += d * d;
  }
  atomicAdd(&ls[c4 + 0], s0); atomicAdd(&ls[c4 + 1], s1);
  atomicAdd(&ls[c4 + 2], s2); atomicAdd(&ls[c4 + 3], s3);
  atomicAdd(&ls[256 + c4 + 0], q0); atomicAdd(&ls[256 + c4 + 1], q1);
  atomicAdd(&ls[256 + c4 + 2], q2); atomicAdd(&ls[256 + c4 + 3], q3);
  __syncthreads();
  atomicAdd(&acc0[tid], ls[tid]);
  atomicAdd(&acc0[256 + tid], ls[256 + tid]);
}

__global__ __launch_bounds__(256) void finalize0_kernel(
    const float* __restrict__ acc0, const float* __restrict__ g0,
    float* __restrict__ st0) {
  int o = threadIdx.x;
  const float inv = 1.0f / 65536.0f;
  float mean = acc0[o] * inv;
  float var = acc0[256 + o] * inv - mean * mean;
  st0[o] = mean;
  st0[256 + o] = g0[o] / sqrtf(var + BN_EPS);
}

// ---- gemm1 (BN+ReLU fused on A-load): y1[b][128][4096] fp32 = W1b*relu(bn(y0t))^T + b1 ----
// grid (32, 2, 16)
__global__ __launch_bounds__(256) void gemm1_kernel(
    const unsigned short* __restrict__ Wb, const unsigned short* __restrict__ y0t,
    const float* __restrict__ st0, const float* __restrict__ be0,
    const float* __restrict__ b1, float* __restrict__ y1) {
  __shared__ short sA[128 * 32];   // 128 n-rows x 32 k  (BN+ReLU'd x1)
  __shared__ short sB[64 * 32];    // 64 o-rows x 32 k
  __shared__ float sst[768];       // mean[256] | scale[256] | beta[256]
  const int b = blockIdx.z, o0 = blockIdx.y * 64, n0 = blockIdx.x * 128;
  const int tid = threadIdx.x, lane = tid & 63, w = tid >> 6;
  const int wm = w & 1, wo2 = w >> 1, quad = lane >> 4, l15 = lane & 15;
  const unsigned short* W1b = Wb + 98304;
  for (int t = tid; t < 768; t += 256)
    sst[t] = (t < 512) ? st0[t] : be0[t - 512];
  floatx4 acc[4][2] = {};
  for (int kb = 0; kb < 256; kb += 32) {
    __syncthreads();
#pragma unroll
    for (int p = 0; p < 2; ++p) {
      int c = p * 256 + tid;
      int r = c >> 2, jj = c & 3;
      short8 raw = *(const short8*)(y0t + (size_t)(b * 4096 + n0 + r) * 256 + kb + jj * 8);
      int kbase = kb + jj * 8;
      short8 v;
#pragma unroll
      for (int u = 0; u < 8; ++u) {
        int k = kbase + u;
        float x = bf2f((unsigned short)raw[u]);
        float rr = fmaxf((x - sst[k]) * sst[256 + k] + sst[512 + k], 0.f);
        v[u] = (short)f2bf(rr);
      }
      *(short8*)(sA + c * 8) = v;
    }
    {
      int r = tid >> 2, jj = tid & 3;
      *(short8*)(sB + tid * 8) =
          *(const short8*)(W1b + (size_t)(o0 + r) * 256 + kb + jj * 8);
    }
    __syncthreads();
    short8 av[4], bv[2];
#pragma unroll
    for (int i = 0; i < 4; ++i)
      av[i] = *(const short8*)(sA + (wm * 64 + i * 16 + l15) * 32 + quad * 8);
#pragma unroll
    for (int j = 0; j < 2; ++j)
      bv[j] = *(const short8*)(sB + (wo2 * 32 + j * 16 + l15) * 32 + quad * 8);
#pragma unroll
    for (int i = 0; i < 4; ++i)
#pragma unroll
      for (int j = 0; j < 2; ++j)
        acc[i][j] = __builtin_amdgcn_mfma_f32_16x16x32_bf16(av[i], bv[j], acc[i][j], 0, 0, 0);
  }
#pragma unroll
  for (int i = 0; i < 4; ++i) {
    int n = n0 + wm * 64 + i * 16 + quad * 4;
#pragma unroll
    for (int j = 0; j < 2; ++j) {
      int o = o0 + wo2 * 32 + j * 16 + l15;
      floatx4 v = acc[i][j] + b1[o];
      *(floatx4*)(y1 + (size_t)(b * 128 + o) * 4096 + n) = v;
    }
  }
}

// ---------------- stats1: per-channel mean + scale (fp32, C=128) ----------------
__global__ __launch_bounds__(256) void stats1_kernel(
    const float* __restrict__ y, const float* __restrict__ g,
    float* __restrict__ st) {
  const int o = blockIdx.x;
  const int tid = threadIdx.x;
  float s = 0.f, ss = 0.f;
  for (int f = tid; f < 16 * 4096; f += 256) {
    int b = f >> 12;
    int n = f & 4095;
    float v = y[(size_t)((b * 128) + o) * 4096 + n];
    s += v; ss += v * v;
  }
  __shared__ float rs[256], rss[256];
  rs[tid] = s; rss[tid] = ss;
  __syncthreads();
  for (int k = 128; k > 0; k >>= 1) {
    if (tid < k) { rs[tid] += rs[tid + k]; rss[tid] += rss[tid + k]; }
    __syncthreads();
  }
  if (tid == 0) {
    const float inv = 1.0f / 65536.0f;
    float mean = rs[0] * inv;
    float var = rss[0] * inv - mean * mean;
    st[o] = mean;
    st[128 + o] = g[o] / sqrtf(var + BN_EPS);
  }
}

// ---------------- bnrelu_f: fp32 in place on d_out ----------------
__global__ __launch_bounds__(256) void bnrelu_f_kernel(
    float* __restrict__ y, const float* __restrict__ st,
    const float* __restrict__ be) {
  size_t i = (size_t)blockIdx.x * 256 + threadIdx.x;
  int o = (int)(i >> 12) & 127;
  float v = y[i];
  float r = (v - st[o]) * st[128 + o] + be[o];
  y[i] = fmaxf(r, 0.f);
}

extern "C" void kernel_launch(void* const* d_in, const int* in_sizes, int n_in,
                              void* d_out, int out_size, void* d_ws, size_t ws_size,
                              hipStream_t stream) {
  (void)in_sizes; (void)n_in; (void)out_size; (void)ws_size;
  const float* xyz1    = (const float*)d_in[0];
  const float* xyz2    = (const float*)d_in[1];
  const float* points1 = (const float*)d_in[2];
  const float* points2 = (const float*)d_in[3];
  const float* W0  = (const float*)d_in[4];
  const float* b0  = (const float*)d_in[5];
  const float* g0  = (const float*)d_in[6];
  const float* be0 = (const float*)d_in[7];
  const float* W1  = (const float*)d_in[8];
  const float* b1  = (const float*)d_in[9];
  const float* g1  = (const float*)d_in[10];
  const float* be1 = (const float*)d_in[11];

  char* ws = (char*)d_ws;
  // layout (bytes), ~58 MB total:
  //   [0,        768K)   idx  int  (B,N1,3)
  //   [768K,     1.5M)   wgt  f32  (B,N1,3)
  //   [1572864,  +2K)    st0  f32[512]
  //   [1574912,  +1K)    st1  f32[256]
  //   [1576960,  +2K)    acc0 f32[512] (zeroed via memset)
  //   [1581056,  +256K)  Wb   bf16 (W0b 98304 ++ W1b 32768)
  //   [2M,       10M)    Xt2  bf16 (B,1024,256)
  //   [10M,      26M)    Xt1  bf16 (B,4096,128)
  //   [26M,      58M)    y0t  bf16 (B,4096,256)  -- raw pre-BN (BN fused into gemm1)
  // Zt fp32 (B,1024,256) = 16 MB lives in d_out front; dead before gemm1.
  int*   idx  = (int*)(ws + 0);
  float* wgt  = (float*)(ws + 786432);
  float* st0  = (float*)(ws + 1572864);
  float* st1  = (float*)(ws + 1574912);
  float* acc0 = (float*)(ws + 1576960);
  unsigned short* Wb  = (unsigned short*)(ws + 1581056);
  unsigned short* Xt2 = (unsigned short*)(ws + 2097152);
  unsigned short* Xt1 = (unsigned short*)(ws + 10485760);
  unsigned short* y0t = (unsigned short*)(ws + 27262976);
  float* Zt = (float*)d_out;
  float* y1 = (float*)d_out;

  cvt_w_kernel<<<512, 256, 0, stream>>>(W0, W1, Wb);
  knn_kernel<<<dim3(128, 16), 256, 0, stream>>>(xyz1, xyz2, idx, wgt);
  tcvt_kernel<<<dim3(16, 4, 16), 256, 0, stream>>>(points2, Xt2, 256, 1024);
  tcvt_kernel<<<dim3(64, 2, 16), 256, 0, stream>>>(points1, Xt1, 128, 4096);
  zgemm_kernel<<<dim3(8, 4, 16), 256, 0, stream>>>(Wb, Xt2, Zt);
  gemm0_kernel<<<dim3(32, 4, 16), 256, 0, stream>>>(Wb, Xt1, Zt, idx, wgt, b0, y0t);
  hipMemsetAsync(acc0, 0, 2048, stream);
  stats0_kernel<<<256, 256, 0, stream>>>(y0t, acc0);
  finalize0_kernel<<<1, 256, 0, stream>>>(acc0, g0, st0);
  gemm1_kernel<<<dim3(32, 2, 16), 256, 0, stream>>>(Wb, y0t, st0, be0, b1, y1);
  stats1_kernel<<<128, 256, 0, stream>>>(y1, g1, st1);
  bnrelu_f_kernel<<<32768, 256, 0, stream>>>(y1, st1, be1);
}

// Round 8
// 291.031 us; speedup vs baseline: 2.5599x; 1.1599x over previous
//
#include <hip/hip_runtime.h>

#define EPS_DIST 1e-10f
#define BN_EPS 1e-5f

typedef short short8 __attribute__((ext_vector_type(8)));
typedef float floatx4 __attribute__((ext_vector_type(4)));

__device__ __forceinline__ unsigned short f2bf(float f) {
  unsigned u = __float_as_uint(f);
  unsigned r = (u + 0x7FFFu + ((u >> 16) & 1u)) >> 16;  // RNE
  return (unsigned short)r;
}
__device__ __forceinline__ float bf2f(unsigned short h) {
  return __uint_as_float(((unsigned)h) << 16);
}

// ---------------- kernel 1: 3-NN + weights, 8 lanes per query ----------------
// grid (128 qtile, 16 b), block 256 (32 queries x 8 lanes)
__global__ __launch_bounds__(256) void knn_kernel(
    const float* __restrict__ xyz1, const float* __restrict__ xyz2,
    int* __restrict__ idxo, float* __restrict__ wo) {
  __shared__ float4 s2[1024];  // x,y,z,|.|^2
  const int b = blockIdx.y;
  const int tid = threadIdx.x;
  const float* x2 = xyz2 + b * 3072;
  for (int j = tid; j < 1024; j += 256) {
    float x = x2[j * 3 + 0], y = x2[j * 3 + 1], z = x2[j * 3 + 2];
    s2[j] = make_float4(x, y, z, (x * x + y * y) + z * z);
  }
  __syncthreads();
  const int q = tid >> 3, sub = tid & 7;
  const int n = blockIdx.x * 32 + q;
  const float* p1 = xyz1 + (b * 4096 + n) * 3;
  const float ax = p1[0], ay = p1[1], az = p1[2];
  const float s1 = (ax * ax + ay * ay) + az * az;
  float d0 = 3.4e38f, d1 = 3.4e38f, d2 = 3.4e38f;
  int i0 = 0x7fffffff, i1 = 0x7fffffff, i2 = 0x7fffffff;
  for (int jj = 0; jj < 128; ++jj) {
    int j = jj * 8 + sub;
    float4 c = s2[j];
    float dot = (ax * c.x + ay * c.y) + az * c.z;
    float d = (s1 + c.w) - 2.0f * dot;
    d = fmaxf(d, EPS_DIST);
    if (d < d2) {
      if (d < d1) {
        d2 = d1; i2 = i1;
        if (d < d0) { d1 = d0; i1 = i0; d0 = d; i0 = j; }
        else { d1 = d; i1 = j; }
      } else { d2 = d; i2 = j; }
    }
  }
  // butterfly merge of sorted (d,idx) triples; lexicographic == lax.top_k order
#pragma unroll
  for (int m = 1; m <= 4; m <<= 1) {
    float e0 = __shfl_xor(d0, m), e1 = __shfl_xor(d1, m), e2 = __shfl_xor(d2, m);
    int   f0 = __shfl_xor(i0, m), f1 = __shfl_xor(i1, m), f2 = __shfl_xor(i2, m);
    float A[3] = {d0, d1, d2}, Bv[3] = {e0, e1, e2};
    int   I[3] = {i0, i1, i2}, J[3] = {f0, f1, f2};
    float md[3]; int mi[3];
    int pa = 0, pb = 0;
#pragma unroll
    for (int k = 0; k < 3; ++k) {
      float da = A[pa], db = Bv[pb];
      int ia = I[pa], ib = J[pb];
      bool ta = (da < db) || (da == db && ia < ib);
      md[k] = ta ? da : db; mi[k] = ta ? ia : ib;
      pa += ta ? 1 : 0; pb += ta ? 0 : 1;
    }
    d0 = md[0]; d1 = md[1]; d2 = md[2];
    i0 = mi[0]; i1 = mi[1]; i2 = mi[2];
  }
  if (sub == 0) {
    float w0 = 1.0f / d0, w1 = 1.0f / d1, w2 = 1.0f / d2;
    float s = (w0 + w1) + w2;
    w0 /= s; w1 /= s; w2 /= s;
    const int base = (b * 4096 + n) * 3;
    idxo[base + 0] = i0; idxo[base + 1] = i1; idxo[base + 2] = i2;
    wo[base + 0] = w0; wo[base + 1] = w1; wo[base + 2] = w2;
  }
}

// ---------------- cvt_w: W0 (256x384) ++ W1 (128x256) -> bf16 ----------------
__global__ __launch_bounds__(256) void cvt_w_kernel(
    const float* __restrict__ W0, const float* __restrict__ W1,
    unsigned short* __restrict__ Wb) {
  int i = blockIdx.x * 256 + threadIdx.x;  // 131072 total
  float v = (i < 98304) ? W0[i] : W1[i - 98304];
  Wb[i] = f2bf(v);
}

// ------- tcvt: src fp32 [B][K][N] -> dst bf16 [B][N][K]; grid (N/64, K/64, B) -------
__global__ __launch_bounds__(256) void tcvt_kernel(
    const float* __restrict__ src, unsigned short* __restrict__ dst,
    int K, int N) {
  __shared__ float sm[64][65];
  const int n0 = blockIdx.x * 64, k0 = blockIdx.y * 64, b = blockIdx.z;
  const int tid = threadIdx.x;
  const int nl = tid & 63, kq = tid >> 6;
  const float* s = src + ((size_t)b * K + k0) * N + n0;
#pragma unroll
  for (int p = 0; p < 16; ++p) {
    int kl = p * 4 + kq;
    sm[kl][nl] = s[(size_t)kl * N + nl];
  }
  __syncthreads();
#pragma unroll
  for (int p = 0; p < 2; ++p) {
    int c = p * 256 + tid;
    int rn = c >> 3, jj = c & 7;
    short8 v;
#pragma unroll
    for (int u = 0; u < 8; ++u) v[u] = (short)f2bf(sm[jj * 8 + u][rn]);
    *(short8*)(dst + (size_t)(b * N + n0 + rn) * K + k0 + jj * 8) = v;
  }
}

// ---- zgemm: Zt[b][1024][256] fp32 = W0b[:,128:384] * Xt2 ; grid (8, 4, 16) ----
__global__ __launch_bounds__(256) void zgemm_kernel(
    const unsigned short* __restrict__ Wb, const unsigned short* __restrict__ Xt2,
    float* __restrict__ Zt) {
  __shared__ short sA[64 * 32];    // 64 o-rows x 32 k
  __shared__ short sB[128 * 32];   // 128 m-rows x 32 k
  const int b = blockIdx.z, o0 = blockIdx.y * 64, m0 = blockIdx.x * 128;
  const int tid = threadIdx.x, lane = tid & 63, w = tid >> 6;
  const int wo = w >> 1, wn = w & 1, quad = lane >> 4, l15 = lane & 15;
  floatx4 acc[2][4] = {};
  for (int kb = 0; kb < 256; kb += 32) {
    __syncthreads();
    {
      int r = tid >> 2, jj = tid & 3;
      *(short8*)(sA + tid * 8) =
          *(const short8*)(Wb + (size_t)(o0 + r) * 384 + 128 + kb + jj * 8);
    }
#pragma unroll
    for (int p = 0; p < 2; ++p) {
      int c = p * 256 + tid;
      int r = c >> 2, jj = c & 3;
      *(short8*)(sB + c * 8) =
          *(const short8*)(Xt2 + (size_t)(b * 1024 + m0 + r) * 256 + kb + jj * 8);
    }
    __syncthreads();
    short8 av[2], bv[4];
#pragma unroll
    for (int i = 0; i < 2; ++i)
      av[i] = *(const short8*)(sA + (wo * 32 + i * 16 + l15) * 32 + quad * 8);
#pragma unroll
    for (int j = 0; j < 4; ++j)
      bv[j] = *(const short8*)(sB + (wn * 64 + j * 16 + l15) * 32 + quad * 8);
#pragma unroll
    for (int i = 0; i < 2; ++i)
#pragma unroll
      for (int j = 0; j < 4; ++j)
        acc[i][j] = __builtin_amdgcn_mfma_f32_16x16x32_bf16(av[i], bv[j], acc[i][j], 0, 0, 0);
  }
#pragma unroll
  for (int i = 0; i < 2; ++i) {
    int ob = o0 + wo * 32 + i * 16 + quad * 4;
#pragma unroll
    for (int j = 0; j < 4; ++j) {
      int m = m0 + wn * 64 + j * 16 + l15;
      *(floatx4*)(Zt + (size_t)(b * 1024 + m) * 256 + ob) = acc[i][j];
    }
  }
}

// -- gemm0 (+fused stats0): y0t = W0b[:,:128]*Xt1 + gather(Zt,w) + b0 ; grid (32,4,16) --
__global__ __launch_bounds__(256) void gemm0_kernel(
    const unsigned short* __restrict__ Wb, const unsigned short* __restrict__ Xt1,
    const float* __restrict__ Zt, const int* __restrict__ idx,
    const float* __restrict__ wgt, const float* __restrict__ b0,
    unsigned short* __restrict__ y0t, float* __restrict__ acc0) {
  __shared__ short sA[64 * 32];    // 64 o-rows x 32 k
  __shared__ short sB[128 * 32];   // 128 n-rows x 32 k
  __shared__ int sidx[384];
  __shared__ float swgt[384];
  __shared__ float ls[128];        // s[64] | ss[64] per local o
  const int b = blockIdx.z, o0 = blockIdx.y * 64, n0 = blockIdx.x * 128;
  const int tid = threadIdx.x, lane = tid & 63, w = tid >> 6;
  const int wo = w >> 1, wn = w & 1, quad = lane >> 4, l15 = lane & 15;
  for (int t = tid; t < 384; t += 256) {
    sidx[t] = idx[(size_t)(b * 4096 + n0) * 3 + t];
    swgt[t] = wgt[(size_t)(b * 4096 + n0) * 3 + t];
  }
  if (tid < 128) ls[tid] = 0.f;
  floatx4 acc[2][4] = {};
  for (int kb = 0; kb < 128; kb += 32) {
    __syncthreads();
    {
      int r = tid >> 2, jj = tid & 3;
      *(short8*)(sA + tid * 8) =
          *(const short8*)(Wb + (size_t)(o0 + r) * 384 + kb + jj * 8);
    }
#pragma unroll
    for (int p = 0; p < 2; ++p) {
      int c = p * 256 + tid;
      int r = c >> 2, jj = c & 3;
      *(short8*)(sB + c * 8) =
          *(const short8*)(Xt1 + (size_t)(b * 4096 + n0 + r) * 128 + kb + jj * 8);
    }
    __syncthreads();
    short8 av[2], bv[4];
#pragma unroll
    for (int i = 0; i < 2; ++i)
      av[i] = *(const short8*)(sA + (wo * 32 + i * 16 + l15) * 32 + quad * 8);
#pragma unroll
    for (int j = 0; j < 4; ++j)
      bv[j] = *(const short8*)(sB + (wn * 64 + j * 16 + l15) * 32 + quad * 8);
#pragma unroll
    for (int i = 0; i < 2; ++i)
#pragma unroll
      for (int j = 0; j < 4; ++j)
        acc[i][j] = __builtin_amdgcn_mfma_f32_16x16x32_bf16(av[i], bv[j], acc[i][j], 0, 0, 0);
  }
  const float* zb = Zt + (size_t)b * 1024 * 256;
#pragma unroll
  for (int i = 0; i < 2; ++i) {
    int ob = o0 + wo * 32 + i * 16 + quad * 4;
    floatx4 bias = *(const floatx4*)(b0 + ob);
    float ps[4] = {0.f, 0.f, 0.f, 0.f}, pq[4] = {0.f, 0.f, 0.f, 0.f};
#pragma unroll
    for (int j = 0; j < 4; ++j) {
      int nl = wn * 64 + j * 16 + l15;
      int n = n0 + nl;
      int g0i = sidx[nl * 3 + 0], g1i = sidx[nl * 3 + 1], g2i = sidx[nl * 3 + 2];
      float gw0 = swgt[nl * 3 + 0], gw1 = swgt[nl * 3 + 1], gw2 = swgt[nl * 3 + 2];
      floatx4 z0 = *(const floatx4*)(zb + (size_t)g0i * 256 + ob);
      floatx4 z1 = *(const floatx4*)(zb + (size_t)g1i * 256 + ob);
      floatx4 z2 = *(const floatx4*)(zb + (size_t)g2i * 256 + ob);
      ushort4 out;
      float v0 = acc[i][j][0] + gw0 * z0[0] + gw1 * z1[0] + gw2 * z2[0] + bias[0];
      float v1 = acc[i][j][1] + gw0 * z0[1] + gw1 * z1[1] + gw2 * z2[1] + bias[1];
      float v2 = acc[i][j][2] + gw0 * z0[2] + gw1 * z1[2] + gw2 * z2[2] + bias[2];
      float v3 = acc[i][j][3] + gw0 * z0[3] + gw1 * z1[3] + gw2 * z2[3] + bias[3];
      out.x = f2bf(v0); out.y = f2bf(v1); out.z = f2bf(v2); out.w = f2bf(v3);
      *(ushort4*)(y0t + (size_t)(b * 4096 + n) * 256 + ob) = out;
      // stats on the ROUNDED values (self-consistent with what gemm1 reads)
      float r0 = bf2f(out.x), r1 = bf2f(out.y), r2 = bf2f(out.z), r3 = bf2f(out.w);
      ps[0] += r0; ps[1] += r1; ps[2] += r2; ps[3] += r3;
      pq[0] += r0 * r0; pq[1] += r1 * r1; pq[2] += r2 * r2; pq[3] += r3 * r3;
    }
    int lo = ob - o0;
#pragma unroll
    for (int u = 0; u < 4; ++u) {
      atomicAdd(&ls[lo + u], ps[u]);
      atomicAdd(&ls[64 + lo + u], pq[u]);
    }
  }
  __syncthreads();
  if (tid < 64) {
    atomicAdd(&acc0[o0 + tid], ls[tid]);
    atomicAdd(&acc0[256 + o0 + tid], ls[64 + tid]);
  }
}

__global__ __launch_bounds__(256) void finalize0_kernel(
    const float* __restrict__ acc0, const float* __restrict__ g0,
    float* __restrict__ st0) {
  int o = threadIdx.x;
  const float inv = 1.0f / 65536.0f;
  float mean = acc0[o] * inv;
  float var = acc0[256 + o] * inv - mean * mean;
  st0[o] = mean;
  st0[256 + o] = g0[o] / sqrtf(var + BN_EPS);
}

// ---- gemm1 (BN+ReLU fused on A-load, fused stats1): y1 = W1b*relu(bn(y0t))^T + b1 ----
// grid (32, 2, 16)
__global__ __launch_bounds__(256) void gemm1_kernel(
    const unsigned short* __restrict__ Wb, const unsigned short* __restrict__ y0t,
    const float* __restrict__ st0, const float* __restrict__ be0,
    const float* __restrict__ b1, float* __restrict__ y1,
    float* __restrict__ acc1) {
  __shared__ short sA[128 * 32];   // 128 n-rows x 32 k  (BN+ReLU'd x1)
  __shared__ short sB[64 * 32];    // 64 o-rows x 32 k
  __shared__ float sst[768];       // mean[256] | scale[256] | beta[256]
  __shared__ float ls[128];        // s[64] | ss[64] per local o
  const int b = blockIdx.z, o0 = blockIdx.y * 64, n0 = blockIdx.x * 128;
  const int tid = threadIdx.x, lane = tid & 63, w = tid >> 6;
  const int wm = w & 1, wo2 = w >> 1, quad = lane >> 4, l15 = lane & 15;
  const unsigned short* W1b = Wb + 98304;
  for (int t = tid; t < 768; t += 256)
    sst[t] = (t < 512) ? st0[t] : be0[t - 512];
  if (tid < 128) ls[tid] = 0.f;
  floatx4 acc[4][2] = {};
  for (int kb = 0; kb < 256; kb += 32) {
    __syncthreads();
#pragma unroll
    for (int p = 0; p < 2; ++p) {
      int c = p * 256 + tid;
      int r = c >> 2, jj = c & 3;
      short8 raw = *(const short8*)(y0t + (size_t)(b * 4096 + n0 + r) * 256 + kb + jj * 8);
      int kbase = kb + jj * 8;
      short8 v;
#pragma unroll
      for (int u = 0; u < 8; ++u) {
        int k = kbase + u;
        float x = bf2f((unsigned short)raw[u]);
        float rr = fmaxf((x - sst[k]) * sst[256 + k] + sst[512 + k], 0.f);
        v[u] = (short)f2bf(rr);
      }
      *(short8*)(sA + c * 8) = v;
    }
    {
      int r = tid >> 2, jj = tid & 3;
      *(short8*)(sB + tid * 8) =
          *(const short8*)(W1b + (size_t)(o0 + r) * 256 + kb + jj * 8);
    }
    __syncthreads();
    short8 av[4], bv[2];
#pragma unroll
    for (int i = 0; i < 4; ++i)
      av[i] = *(const short8*)(sA + (wm * 64 + i * 16 + l15) * 32 + quad * 8);
#pragma unroll
    for (int j = 0; j < 2; ++j)
      bv[j] = *(const short8*)(sB + (wo2 * 32 + j * 16 + l15) * 32 + quad * 8);
#pragma unroll
    for (int i = 0; i < 4; ++i)
#pragma unroll
      for (int j = 0; j < 2; ++j)
        acc[i][j] = __builtin_amdgcn_mfma_f32_16x16x32_bf16(av[i], bv[j], acc[i][j], 0, 0, 0);
  }
#pragma unroll
  for (int j = 0; j < 2; ++j) {
    int o = o0 + wo2 * 32 + j * 16 + l15;
    float bias = b1[o];
    float s = 0.f, q = 0.f;
#pragma unroll
    for (int i = 0; i < 4; ++i) {
      int n = n0 + wm * 64 + i * 16 + quad * 4;
      floatx4 v = acc[i][j] + bias;
      *(floatx4*)(y1 + (size_t)(b * 128 + o) * 4096 + n) = v;
      s += (v[0] + v[1]) + (v[2] + v[3]);
      q += (v[0] * v[0] + v[1] * v[1]) + (v[2] * v[2] + v[3] * v[3]);
    }
    atomicAdd(&ls[o - o0], s);
    atomicAdd(&ls[64 + (o - o0)], q);
  }
  __syncthreads();
  if (tid < 64) {
    atomicAdd(&acc1[o0 + tid], ls[tid]);
    atomicAdd(&acc1[128 + o0 + tid], ls[64 + tid]);
  }
}

__global__ __launch_bounds__(128) void finalize1_kernel(
    const float* __restrict__ acc1, const float* __restrict__ g1,
    float* __restrict__ st1) {
  int o = threadIdx.x;
  const float inv = 1.0f / 65536.0f;
  float mean = acc1[o] * inv;
  float var = acc1[128 + o] * inv - mean * mean;
  st1[o] = mean;
  st1[128 + o] = g1[o] / sqrtf(var + BN_EPS);
}

// ---------------- bnrelu_f: fp32 in place on d_out, float4/thread ----------------
// grid 8192 x 256
__global__ __launch_bounds__(256) void bnrelu_f_kernel(
    float* __restrict__ y, const float* __restrict__ st,
    const float* __restrict__ be) {
  size_t i4 = (size_t)blockIdx.x * 256 + threadIdx.x;
  int o = (int)((i4 * 4) >> 12) & 127;
  float m = st[o], sc = st[128 + o], bb = be[o];
  floatx4 v = ((floatx4*)y)[i4];
  floatx4 r;
  r[0] = fmaxf((v[0] - m) * sc + bb, 0.f);
  r[1] = fmaxf((v[1] - m) * sc + bb, 0.f);
  r[2] = fmaxf((v[2] - m) * sc + bb, 0.f);
  r[3] = fmaxf((v[3] - m) * sc + bb, 0.f);
  ((floatx4*)y)[i4] = r;
}

extern "C" void kernel_launch(void* const* d_in, const int* in_sizes, int n_in,
                              void* d_out, int out_size, void* d_ws, size_t ws_size,
                              hipStream_t stream) {
  (void)in_sizes; (void)n_in; (void)out_size; (void)ws_size;
  const float* xyz1    = (const float*)d_in[0];
  const float* xyz2    = (const float*)d_in[1];
  const float* points1 = (const float*)d_in[2];
  const float* points2 = (const float*)d_in[3];
  const float* W0  = (const float*)d_in[4];
  const float* b0  = (const float*)d_in[5];
  const float* g0  = (const float*)d_in[6];
  const float* be0 = (const float*)d_in[7];
  const float* W1  = (const float*)d_in[8];
  const float* b1  = (const float*)d_in[9];
  const float* g1  = (const float*)d_in[10];
  const float* be1 = (const float*)d_in[11];

  char* ws = (char*)d_ws;
  // layout (bytes), ~58 MB total:
  //   [0,        768K)   idx  int  (B,N1,3)
  //   [768K,     1.5M)   wgt  f32  (B,N1,3)
  //   [1572864,  +2K)    st0  f32[512]
  //   [1574912,  +1K)    st1  f32[256]
  //   [1576960,  +2K)    acc0 f32[512]   } zeroed by one 3072B memset
  //   [1579008,  +1K)    acc1 f32[256]   }
  //   [1581056,  +256K)  Wb   bf16 (W0b 98304 ++ W1b 32768)
  //   [2M,       10M)    Xt2  bf16 (B,1024,256)
  //   [10M,      26M)    Xt1  bf16 (B,4096,128)
  //   [26M,      58M)    y0t  bf16 (B,4096,256)  -- raw pre-BN (BN fused into gemm1)
  // Zt fp32 (B,1024,256) = 16 MB lives in d_out front; dead before gemm1.
  int*   idx  = (int*)(ws + 0);
  float* wgt  = (float*)(ws + 786432);
  float* st0  = (float*)(ws + 1572864);
  float* st1  = (float*)(ws + 1574912);
  float* acc0 = (float*)(ws + 1576960);
  float* acc1 = (float*)(ws + 1579008);
  unsigned short* Wb  = (unsigned short*)(ws + 1581056);
  unsigned short* Xt2 = (unsigned short*)(ws + 2097152);
  unsigned short* Xt1 = (unsigned short*)(ws + 10485760);
  unsigned short* y0t = (unsigned short*)(ws + 27262976);
  float* Zt = (float*)d_out;
  float* y1 = (float*)d_out;

  hipMemsetAsync(acc0, 0, 3072, stream);
  cvt_w_kernel<<<512, 256, 0, stream>>>(W0, W1, Wb);
  knn_kernel<<<dim3(128, 16), 256, 0, stream>>>(xyz1, xyz2, idx, wgt);
  tcvt_kernel<<<dim3(16, 4, 16), 256, 0, stream>>>(points2, Xt2, 256, 1024);
  tcvt_kernel<<<dim3(64, 2, 16), 256, 0, stream>>>(points1, Xt1, 128, 4096);
  zgemm_kernel<<<dim3(8, 4, 16), 256, 0, stream>>>(Wb, Xt2, Zt);
  gemm0_kernel<<<dim3(32, 4, 16), 256, 0, stream>>>(Wb, Xt1, Zt, idx, wgt, b0, y0t, acc0);
  finalize0_kernel<<<1, 256, 0, stream>>>(acc0, g0, st0);
  gemm1_kernel<<<dim3(32, 2, 16), 256, 0, stream>>>(Wb, y0t, st0, be0, b1, y1, acc1);
  finalize1_kernel<<<1, 128, 0, stream>>>(acc1, g1, st1);
  bnrelu_f_kernel<<<8192, 256, 0, stream>>>(y1, st1, be1);
}

// Round 9
// 289.258 us; speedup vs baseline: 2.5756x; 1.0061x over previous
//
#include <hip/hip_runtime.h>

#define EPS_DIST 1e-10f
#define BN_EPS 1e-5f

typedef short short8 __attribute__((ext_vector_type(8)));
typedef float floatx4 __attribute__((ext_vector_type(4)));

__device__ __forceinline__ unsigned short f2bf(float f) {
  unsigned u = __float_as_uint(f);
  unsigned r = (u + 0x7FFFu + ((u >> 16) & 1u)) >> 16;  // RNE
  return (unsigned short)r;
}
__device__ __forceinline__ float bf2f(unsigned short h) {
  return __uint_as_float(((unsigned)h) << 16);
}

// ---------------- kernel 1: 3-NN + weights, 8 lanes per query ----------------
// grid (128 qtile, 16 b), block 256 (32 queries x 8 lanes)
__global__ __launch_bounds__(256) void knn_kernel(
    const float* __restrict__ xyz1, const float* __restrict__ xyz2,
    int* __restrict__ idxo, float* __restrict__ wo) {
  __shared__ float4 s2[1024];  // x,y,z,|.|^2
  const int b = blockIdx.y;
  const int tid = threadIdx.x;
  const float* x2 = xyz2 + b * 3072;
  for (int j = tid; j < 1024; j += 256) {
    float x = x2[j * 3 + 0], y = x2[j * 3 + 1], z = x2[j * 3 + 2];
    s2[j] = make_float4(x, y, z, (x * x + y * y) + z * z);
  }
  __syncthreads();
  const int q = tid >> 3, sub = tid & 7;
  const int n = blockIdx.x * 32 + q;
  const float* p1 = xyz1 + (b * 4096 + n) * 3;
  const float ax = p1[0], ay = p1[1], az = p1[2];
  const float s1 = (ax * ax + ay * ay) + az * az;
  float d0 = 3.4e38f, d1 = 3.4e38f, d2 = 3.4e38f;
  int i0 = 0x7fffffff, i1 = 0x7fffffff, i2 = 0x7fffffff;
  for (int jj = 0; jj < 128; ++jj) {
    int j = jj * 8 + sub;
    float4 c = s2[j];
    float dot = (ax * c.x + ay * c.y) + az * c.z;
    float d = (s1 + c.w) - 2.0f * dot;
    d = fmaxf(d, EPS_DIST);
    if (d < d2) {
      if (d < d1) {
        d2 = d1; i2 = i1;
        if (d < d0) { d1 = d0; i1 = i0; d0 = d; i0 = j; }
        else { d1 = d; i1 = j; }
      } else { d2 = d; i2 = j; }
    }
  }
  // butterfly merge of sorted (d,idx) triples; lexicographic == lax.top_k order
#pragma unroll
  for (int m = 1; m <= 4; m <<= 1) {
    float e0 = __shfl_xor(d0, m), e1 = __shfl_xor(d1, m), e2 = __shfl_xor(d2, m);
    int   f0 = __shfl_xor(i0, m), f1 = __shfl_xor(i1, m), f2 = __shfl_xor(i2, m);
    float A[3] = {d0, d1, d2}, Bv[3] = {e0, e1, e2};
    int   I[3] = {i0, i1, i2}, J[3] = {f0, f1, f2};
    float md[3]; int mi[3];
    int pa = 0, pb = 0;
#pragma unroll
    for (int k = 0; k < 3; ++k) {
      float da = A[pa], db = Bv[pb];
      int ia = I[pa], ib = J[pb];
      bool ta = (da < db) || (da == db && ia < ib);
      md[k] = ta ? da : db; mi[k] = ta ? ia : ib;
      pa += ta ? 1 : 0; pb += ta ? 0 : 1;
    }
    d0 = md[0]; d1 = md[1]; d2 = md[2];
    i0 = mi[0]; i1 = mi[1]; i2 = mi[2];
  }
  if (sub == 0) {
    float w0 = 1.0f / d0, w1 = 1.0f / d1, w2 = 1.0f / d2;
    float s = (w0 + w1) + w2;
    w0 /= s; w1 /= s; w2 /= s;
    const int base = (b * 4096 + n) * 3;
    idxo[base + 0] = i0; idxo[base + 1] = i1; idxo[base + 2] = i2;
    wo[base + 0] = w0; wo[base + 1] = w1; wo[base + 2] = w2;
  }
}

// ---------------- cvt_w: W0 (256x384) ++ W1 (128x256) -> bf16 ----------------
__global__ __launch_bounds__(256) void cvt_w_kernel(
    const float* __restrict__ W0, const float* __restrict__ W1,
    unsigned short* __restrict__ Wb) {
  int i = blockIdx.x * 256 + threadIdx.x;  // 131072 total
  float v = (i < 98304) ? W0[i] : W1[i - 98304];
  Wb[i] = f2bf(v);
}

// ------- tcvt: src fp32 [B][K][N] -> dst bf16 [B][N][K]; grid (N/64, K/64, B) -------
__global__ __launch_bounds__(256) void tcvt_kernel(
    const float* __restrict__ src, unsigned short* __restrict__ dst,
    int K, int N) {
  __shared__ float sm[64][65];
  const int n0 = blockIdx.x * 64, k0 = blockIdx.y * 64, b = blockIdx.z;
  const int tid = threadIdx.x;
  const int nl = tid & 63, kq = tid >> 6;
  const float* s = src + ((size_t)b * K + k0) * N + n0;
#pragma unroll
  for (int p = 0; p < 16; ++p) {
    int kl = p * 4 + kq;
    sm[kl][nl] = s[(size_t)kl * N + nl];
  }
  __syncthreads();
#pragma unroll
  for (int p = 0; p < 2; ++p) {
    int c = p * 256 + tid;
    int rn = c >> 3, jj = c & 7;
    short8 v;
#pragma unroll
    for (int u = 0; u < 8; ++u) v[u] = (short)f2bf(sm[jj * 8 + u][rn]);
    *(short8*)(dst + (size_t)(b * N + n0 + rn) * K + k0 + jj * 8) = v;
  }
}

// ---- zgemm: Zt[b][1024][256] BF16 = W0b[:,128:384] * Xt2 ; grid (8, 4, 16) ----
__global__ __launch_bounds__(256) void zgemm_kernel(
    const unsigned short* __restrict__ Wb, const unsigned short* __restrict__ Xt2,
    unsigned short* __restrict__ Zt) {
  __shared__ short sA[64 * 32];    // 64 o-rows x 32 k
  __shared__ short sB[128 * 32];   // 128 m-rows x 32 k
  const int b = blockIdx.z, o0 = blockIdx.y * 64, m0 = blockIdx.x * 128;
  const int tid = threadIdx.x, lane = tid & 63, w = tid >> 6;
  const int wo = w >> 1, wn = w & 1, quad = lane >> 4, l15 = lane & 15;
  floatx4 acc[2][4] = {};
  for (int kb = 0; kb < 256; kb += 32) {
    __syncthreads();
    {
      int r = tid >> 2, jj = tid & 3;
      *(short8*)(sA + tid * 8) =
          *(const short8*)(Wb + (size_t)(o0 + r) * 384 + 128 + kb + jj * 8);
    }
#pragma unroll
    for (int p = 0; p < 2; ++p) {
      int c = p * 256 + tid;
      int r = c >> 2, jj = c & 3;
      *(short8*)(sB + c * 8) =
          *(const short8*)(Xt2 + (size_t)(b * 1024 + m0 + r) * 256 + kb + jj * 8);
    }
    __syncthreads();
    short8 av[2], bv[4];
#pragma unroll
    for (int i = 0; i < 2; ++i)
      av[i] = *(const short8*)(sA + (wo * 32 + i * 16 + l15) * 32 + quad * 8);
#pragma unroll
    for (int j = 0; j < 4; ++j)
      bv[j] = *(const short8*)(sB + (wn * 64 + j * 16 + l15) * 32 + quad * 8);
#pragma unroll
    for (int i = 0; i < 2; ++i)
#pragma unroll
      for (int j = 0; j < 4; ++j)
        acc[i][j] = __builtin_amdgcn_mfma_f32_16x16x32_bf16(av[i], bv[j], acc[i][j], 0, 0, 0);
  }
#pragma unroll
  for (int i = 0; i < 2; ++i) {
    int ob = o0 + wo * 32 + i * 16 + quad * 4;
#pragma unroll
    for (int j = 0; j < 4; ++j) {
      int m = m0 + wn * 64 + j * 16 + l15;
      ushort4 out;
      out.x = f2bf(acc[i][j][0]); out.y = f2bf(acc[i][j][1]);
      out.z = f2bf(acc[i][j][2]); out.w = f2bf(acc[i][j][3]);
      *(ushort4*)(Zt + (size_t)(b * 1024 + m) * 256 + ob) = out;
    }
  }
}

// -- gemm0 (+fused stats0): y0t = W0b[:,:128]*Xt1 + gather(Zt,w) + b0
//    o-tile 128, n-tile 128; grid (32, 2, 16) --
__global__ __launch_bounds__(256) void gemm0_kernel(
    const unsigned short* __restrict__ Wb, const unsigned short* __restrict__ Xt1,
    const unsigned short* __restrict__ Zt, const int* __restrict__ idx,
    const float* __restrict__ wgt, const float* __restrict__ b0,
    unsigned short* __restrict__ y0t, float* __restrict__ acc0) {
  __shared__ short sA[128 * 32];   // 128 o-rows x 32 k
  __shared__ short sB[128 * 32];   // 128 n-rows x 32 k
  __shared__ int sidx[384];
  __shared__ float swgt[384];
  __shared__ float ls[256];        // s[128] | ss[128] per local o
  const int b = blockIdx.z, o0 = blockIdx.y * 128, n0 = blockIdx.x * 128;
  const int tid = threadIdx.x, lane = tid & 63, w = tid >> 6;
  const int wo = w >> 1, wn = w & 1, quad = lane >> 4, l15 = lane & 15;
  for (int t = tid; t < 384; t += 256) {
    sidx[t] = idx[(size_t)(b * 4096 + n0) * 3 + t];
    swgt[t] = wgt[(size_t)(b * 4096 + n0) * 3 + t];
  }
  if (tid < 256) ls[tid] = 0.f;
  floatx4 acc[4][4] = {};
  for (int kb = 0; kb < 128; kb += 32) {
    __syncthreads();
#pragma unroll
    for (int p = 0; p < 2; ++p) {
      int c = p * 256 + tid;
      int r = c >> 2, jj = c & 3;
      *(short8*)(sA + c * 8) =
          *(const short8*)(Wb + (size_t)(o0 + r) * 384 + kb + jj * 8);
    }
#pragma unroll
    for (int p = 0; p < 2; ++p) {
      int c = p * 256 + tid;
      int r = c >> 2, jj = c & 3;
      *(short8*)(sB + c * 8) =
          *(const short8*)(Xt1 + (size_t)(b * 4096 + n0 + r) * 128 + kb + jj * 8);
    }
    __syncthreads();
    short8 av[4], bv[4];
#pragma unroll
    for (int i = 0; i < 4; ++i)
      av[i] = *(const short8*)(sA + (wo * 64 + i * 16 + l15) * 32 + quad * 8);
#pragma unroll
    for (int j = 0; j < 4; ++j)
      bv[j] = *(const short8*)(sB + (wn * 64 + j * 16 + l15) * 32 + quad * 8);
#pragma unroll
    for (int i = 0; i < 4; ++i)
#pragma unroll
      for (int j = 0; j < 4; ++j)
        acc[i][j] = __builtin_amdgcn_mfma_f32_16x16x32_bf16(av[i], bv[j], acc[i][j], 0, 0, 0);
  }
  const unsigned short* zb = Zt + (size_t)b * 1024 * 256;
#pragma unroll
  for (int i = 0; i < 4; ++i) {
    int obg = o0 + wo * 64 + i * 16 + quad * 4;   // global o
    floatx4 bias = *(const floatx4*)(b0 + obg);
    float ps[4] = {0.f, 0.f, 0.f, 0.f}, pq[4] = {0.f, 0.f, 0.f, 0.f};
#pragma unroll
    for (int j = 0; j < 4; ++j) {
      int nl = wn * 64 + j * 16 + l15;
      int n = n0 + nl;
      int g0i = sidx[nl * 3 + 0], g1i = sidx[nl * 3 + 1], g2i = sidx[nl * 3 + 2];
      float gw0 = swgt[nl * 3 + 0], gw1 = swgt[nl * 3 + 1], gw2 = swgt[nl * 3 + 2];
      ushort4 zr0 = *(const ushort4*)(zb + (size_t)g0i * 256 + obg);
      ushort4 zr1 = *(const ushort4*)(zb + (size_t)g1i * 256 + obg);
      ushort4 zr2 = *(const ushort4*)(zb + (size_t)g2i * 256 + obg);
      ushort4 out;
      float v0 = acc[i][j][0] + gw0 * bf2f(zr0.x) + gw1 * bf2f(zr1.x) + gw2 * bf2f(zr2.x) + bias[0];
      float v1 = acc[i][j][1] + gw0 * bf2f(zr0.y) + gw1 * bf2f(zr1.y) + gw2 * bf2f(zr2.y) + bias[1];
      float v2 = acc[i][j][2] + gw0 * bf2f(zr0.z) + gw1 * bf2f(zr1.z) + gw2 * bf2f(zr2.z) + bias[2];
      float v3 = acc[i][j][3] + gw0 * bf2f(zr0.w) + gw1 * bf2f(zr1.w) + gw2 * bf2f(zr2.w) + bias[3];
      out.x = f2bf(v0); out.y = f2bf(v1); out.z = f2bf(v2); out.w = f2bf(v3);
      *(ushort4*)(y0t + (size_t)(b * 4096 + n) * 256 + obg) = out;
      // stats on the ROUNDED values (self-consistent with what gemm1 reads)
      float r0 = bf2f(out.x), r1 = bf2f(out.y), r2 = bf2f(out.z), r3 = bf2f(out.w);
      ps[0] += r0; ps[1] += r1; ps[2] += r2; ps[3] += r3;
      pq[0] += r0 * r0; pq[1] += r1 * r1; pq[2] += r2 * r2; pq[3] += r3 * r3;
    }
    int lo = obg - o0;
#pragma unroll
    for (int u = 0; u < 4; ++u) {
      atomicAdd(&ls[lo + u], ps[u]);
      atomicAdd(&ls[128 + lo + u], pq[u]);
    }
  }
  __syncthreads();
  if (tid < 128) {
    atomicAdd(&acc0[o0 + tid], ls[tid]);
    atomicAdd(&acc0[256 + o0 + tid], ls[128 + tid]);
  }
}

// finalize0: st0[o] = scale, st0[256+o] = offset  (BN folded: y = x*scale + offset)
__global__ __launch_bounds__(256) void finalize0_kernel(
    const float* __restrict__ acc0, const float* __restrict__ g0,
    const float* __restrict__ be0, float* __restrict__ st0) {
  int o = threadIdx.x;
  const float inv = 1.0f / 65536.0f;
  float mean = acc0[o] * inv;
  float var = acc0[256 + o] * inv - mean * mean;
  float sc = g0[o] / sqrtf(var + BN_EPS);
  st0[o] = sc;
  st0[256 + o] = be0[o] - mean * sc;
}

// ---- gemm1 (BN+ReLU fused on A-load, fused stats1): y1 = W1b*relu(bn(y0t))^T + b1
//      full o=128 per block; grid (32, 16) ----
__global__ __launch_bounds__(256) void gemm1_kernel(
    const unsigned short* __restrict__ Wb, const unsigned short* __restrict__ y0t,
    const float* __restrict__ st0, const float* __restrict__ b1,
    float* __restrict__ y1, float* __restrict__ acc1) {
  __shared__ short sA[128 * 32];   // 128 n-rows x 32 k  (BN+ReLU'd x1)
  __shared__ short sB[128 * 32];   // 128 o-rows x 32 k
  __shared__ float sst[512];       // scale[256] | offset[256]
  __shared__ float ls[256];        // s[128] | ss[128]
  const int b = blockIdx.y, n0 = blockIdx.x * 128;
  const int tid = threadIdx.x, lane = tid & 63, w = tid >> 6;
  const int wm = w & 1, wo2 = w >> 1, quad = lane >> 4, l15 = lane & 15;
  const unsigned short* W1b = Wb + 98304;
  for (int t = tid; t < 512; t += 256) sst[t] = st0[t];
  if (tid < 256) ls[tid] = 0.f;
  floatx4 acc[4][4] = {};
  for (int kb = 0; kb < 256; kb += 32) {
    __syncthreads();
#pragma unroll
    for (int p = 0; p < 2; ++p) {
      int c = p * 256 + tid;
      int r = c >> 2, jj = c & 3;
      short8 raw = *(const short8*)(y0t + (size_t)(b * 4096 + n0 + r) * 256 + kb + jj * 8);
      int kbase = kb + jj * 8;
      short8 v;
#pragma unroll
      for (int u = 0; u < 8; ++u) {
        int k = kbase + u;
        float rr = fmaxf(bf2f((unsigned short)raw[u]) * sst[k] + sst[256 + k], 0.f);
        v[u] = (short)f2bf(rr);
      }
      *(short8*)(sA + c * 8) = v;
    }
#pragma unroll
    for (int p = 0; p < 2; ++p) {
      int c = p * 256 + tid;
      int r = c >> 2, jj = c & 3;
      *(short8*)(sB + c * 8) =
          *(const short8*)(W1b + (size_t)r * 256 + kb + jj * 8);
    }
    __syncthreads();
    short8 av[4], bv[4];
#pragma unroll
    for (int i = 0; i < 4; ++i)
      av[i] = *(const short8*)(sA + (wm * 64 + i * 16 + l15) * 32 + quad * 8);
#pragma unroll
    for (int j = 0; j < 4; ++j)
      bv[j] = *(const short8*)(sB + (wo2 * 64 + j * 16 + l15) * 32 + quad * 8);
#pragma unroll
    for (int i = 0; i < 4; ++i)
#pragma unroll
      for (int j = 0; j < 4; ++j)
        acc[i][j] = __builtin_amdgcn_mfma_f32_16x16x32_bf16(av[i], bv[j], acc[i][j], 0, 0, 0);
  }
#pragma unroll
  for (int j = 0; j < 4; ++j) {
    int o = wo2 * 64 + j * 16 + l15;
    float bias = b1[o];
    float s = 0.f, q = 0.f;
#pragma unroll
    for (int i = 0; i < 4; ++i) {
      int n = n0 + wm * 64 + i * 16 + quad * 4;
      floatx4 v = acc[i][j] + bias;
      *(floatx4*)(y1 + (size_t)(b * 128 + o) * 4096 + n) = v;
      s += (v[0] + v[1]) + (v[2] + v[3]);
      q += (v[0] * v[0] + v[1] * v[1]) + (v[2] * v[2] + v[3] * v[3]);
    }
    atomicAdd(&ls[o], s);
    atomicAdd(&ls[128 + o], q);
  }
  __syncthreads();
  if (tid < 128) {
    atomicAdd(&acc1[tid], ls[tid]);
    atomicAdd(&acc1[128 + tid], ls[128 + tid]);
  }
}

__global__ __launch_bounds__(128) void finalize1_kernel(
    const float* __restrict__ acc1, const float* __restrict__ g1,
    float* __restrict__ st1) {
  int o = threadIdx.x;
  const float inv = 1.0f / 65536.0f;
  float mean = acc1[o] * inv;
  float var = acc1[128 + o] * inv - mean * mean;
  st1[o] = mean;
  st1[128 + o] = g1[o] / sqrtf(var + BN_EPS);
}

// ---------------- bnrelu_f: fp32 in place on d_out, float4/thread ----------------
// grid 8192 x 256
__global__ __launch_bounds__(256) void bnrelu_f_kernel(
    float* __restrict__ y, const float* __restrict__ st,
    const float* __restrict__ be) {
  size_t i4 = (size_t)blockIdx.x * 256 + threadIdx.x;
  int o = (int)((i4 * 4) >> 12) & 127;
  float m = st[o], sc = st[128 + o], bb = be[o];
  floatx4 v = ((floatx4*)y)[i4];
  floatx4 r;
  r[0] = fmaxf((v[0] - m) * sc + bb, 0.f);
  r[1] = fmaxf((v[1] - m) * sc + bb, 0.f);
  r[2] = fmaxf((v[2] - m) * sc + bb, 0.f);
  r[3] = fmaxf((v[3] - m) * sc + bb, 0.f);
  ((floatx4*)y)[i4] = r;
}

extern "C" void kernel_launch(void* const* d_in, const int* in_sizes, int n_in,
                              void* d_out, int out_size, void* d_ws, size_t ws_size,
                              hipStream_t stream) {
  (void)in_sizes; (void)n_in; (void)out_size; (void)ws_size;
  const float* xyz1    = (const float*)d_in[0];
  const float* xyz2    = (const float*)d_in[1];
  const float* points1 = (const float*)d_in[2];
  const float* points2 = (const float*)d_in[3];
  const float* W0  = (const float*)d_in[4];
  const float* b0  = (const float*)d_in[5];
  const float* g0  = (const float*)d_in[6];
  const float* be0 = (const float*)d_in[7];
  const float* W1  = (const float*)d_in[8];
  const float* b1  = (const float*)d_in[9];
  const float* g1  = (const float*)d_in[10];
  const float* be1 = (const float*)d_in[11];

  char* ws = (char*)d_ws;
  // layout (bytes), ~58 MB total:
  //   [0,        768K)   idx  int  (B,N1,3)
  //   [768K,     1.5M)   wgt  f32  (B,N1,3)
  //   [1572864,  +2K)    st0  f32[512]  (scale|offset)
  //   [1574912,  +1K)    st1  f32[256]
  //   [1576960,  +2K)    acc0 f32[512]   } zeroed by one 3072B memset
  //   [1579008,  +1K)    acc1 f32[256]   }
  //   [1581056,  +256K)  Wb   bf16 (W0b 98304 ++ W1b 32768)
  //   [2M,       10M)    Xt2  bf16 (B,1024,256)
  //   [10M,      26M)    Xt1  bf16 (B,4096,128)
  //   [26M,      58M)    y0t  bf16 (B,4096,256)  -- raw pre-BN (BN fused into gemm1)
  // Zt BF16 (B,1024,256) = 8.4 MB lives in d_out front; dead before gemm1.
  int*   idx  = (int*)(ws + 0);
  float* wgt  = (float*)(ws + 786432);
  float* st0  = (float*)(ws + 1572864);
  float* st1  = (float*)(ws + 1574912);
  float* acc0 = (float*)(ws + 1576960);
  float* acc1 = (float*)(ws + 1579008);
  unsigned short* Wb  = (unsigned short*)(ws + 1581056);
  unsigned short* Xt2 = (unsigned short*)(ws + 2097152);
  unsigned short* Xt1 = (unsigned short*)(ws + 10485760);
  unsigned short* y0t = (unsigned short*)(ws + 27262976);
  unsigned short* Zt = (unsigned short*)d_out;
  float* y1 = (float*)d_out;

  hipMemsetAsync(acc0, 0, 3072, stream);
  cvt_w_kernel<<<512, 256, 0, stream>>>(W0, W1, Wb);
  knn_kernel<<<dim3(128, 16), 256, 0, stream>>>(xyz1, xyz2, idx, wgt);
  tcvt_kernel<<<dim3(16, 4, 16), 256, 0, stream>>>(points2, Xt2, 256, 1024);
  tcvt_kernel<<<dim3(64, 2, 16), 256, 0, stream>>>(points1, Xt1, 128, 4096);
  zgemm_kernel<<<dim3(8, 4, 16), 256, 0, stream>>>(Wb, Xt2, Zt);
  gemm0_kernel<<<dim3(32, 2, 16), 256, 0, stream>>>(Wb, Xt1, Zt, idx, wgt, b0, y0t, acc0);
  finalize0_kernel<<<1, 256, 0, stream>>>(acc0, g0, be0, st0);
  gemm1_kernel<<<dim3(32, 16), 256, 0, stream>>>(Wb, y0t, st0, b1, y1, acc1);
  finalize1_kernel<<<1, 128, 0, stream>>>(acc1, g1, st1);
  bnrelu_f_kernel<<<8192, 256, 0, stream>>>(y1, st1, be1);
}